// Round 9
// baseline (4587.638 us; speedup 1.0000x reference)
//
#include <hip/hip_runtime.h>
#include <hip/hip_bf16.h>
#include <cstdint>

#define N_NODES 100000
#define N_EDGES 3200000
#define HID 256
#define NG 16
#define BN_EPS 1e-5f
#define B0 120       // bn0stats partial blocks
#define PB 1024      // stats partial blocks
#define SROWS ((N_NODES + PB - 1) / PB)   // 98 rows per stats block
#define PBR 128      // second-stage reduction blocks
#define RPR (PB / PBR)                    // 8 partial rows per reduce block

typedef unsigned short u16;
using bf16x8 = __attribute__((ext_vector_type(8))) short;
using f32x4  = __attribute__((ext_vector_type(4))) float;

__device__ __forceinline__ float bf2f(u16 b) {
    return __uint_as_float(((unsigned)b) << 16);
}
__device__ __forceinline__ u16 f2bf(float f) {
    unsigned u = __float_as_uint(f);
    unsigned r = (u + 0x7FFFu + ((u >> 16) & 1u)) >> 16;
    return (u16)r;
}
__device__ __forceinline__ float4 ld_bf16x4(const u16* p) {
    ushort4 u = *reinterpret_cast<const ushort4*>(p);
    float4 f;
    f.x = bf2f(u.x); f.y = bf2f(u.y); f.z = bf2f(u.z); f.w = bf2f(u.w);
    return f;
}

// ---------------- CSR build ----------------
__global__ void k_count(const int* __restrict__ coli, int* __restrict__ cnt) {
    int i = blockIdx.x * blockDim.x + threadIdx.x;
    int st = gridDim.x * blockDim.x;
    for (; i < N_EDGES; i += st) atomicAdd(&cnt[coli[i]], 1);
}

// 1024-thread single-block scan (wave-shuffle) + fused dinv; writes ptr AND ptr2
__global__ void k_scan(const int* __restrict__ cnt, int* __restrict__ ptr,
                       int* __restrict__ ptr2, float* __restrict__ dinv) {
    __shared__ int wsum[16];
    const int t = threadIdx.x;
    const int wv = t >> 6;
    const int ln = t & 63;
    int carry = 0;
    for (int base = 0; base < N_NODES; base += 4096) {
        int idx = base + t * 4;
        int v0 = 0, v1 = 0, v2 = 0, v3 = 0;
        if (idx + 3 < N_NODES) {
            int4 q = *reinterpret_cast<const int4*>(&cnt[idx]);
            v0 = q.x; v1 = q.y; v2 = q.z; v3 = q.w;
        } else {
            if (idx + 0 < N_NODES) v0 = cnt[idx + 0];
            if (idx + 1 < N_NODES) v1 = cnt[idx + 1];
            if (idx + 2 < N_NODES) v2 = cnt[idx + 2];
        }
        if (idx + 0 < N_NODES) dinv[idx + 0] = rsqrtf((float)v0 + 1.0f);
        if (idx + 1 < N_NODES) dinv[idx + 1] = rsqrtf((float)v1 + 1.0f);
        if (idx + 2 < N_NODES) dinv[idx + 2] = rsqrtf((float)v2 + 1.0f);
        if (idx + 3 < N_NODES) dinv[idx + 3] = rsqrtf((float)v3 + 1.0f);
        int s = v0 + v1 + v2 + v3;
        int sc = s;
        for (int off = 1; off < 64; off <<= 1) {
            int u = __shfl_up(sc, off);
            if (ln >= off) sc += u;
        }
        if (ln == 63) wsum[wv] = sc;
        __syncthreads();
        if (wv == 0 && ln < 16) {
            int a = wsum[ln];
            for (int off = 1; off < 16; off <<= 1) {
                int u = __shfl_up(a, off, 16);
                if (ln >= off) a += u;
            }
            wsum[ln] = a;
        }
        __syncthreads();
        int total = wsum[15];
        int excl = carry + (wv ? wsum[wv - 1] : 0) + sc - s;
        if (idx + 0 < N_NODES) { ptr[idx + 0] = excl; ptr2[idx + 0] = excl; } excl += v0;
        if (idx + 1 < N_NODES) { ptr[idx + 1] = excl; ptr2[idx + 1] = excl; } excl += v1;
        if (idx + 2 < N_NODES) { ptr[idx + 2] = excl; ptr2[idx + 2] = excl; } excl += v2;
        if (idx + 3 < N_NODES) { ptr[idx + 3] = excl; ptr2[idx + 3] = excl; }
        __syncthreads();
        carry += total;
    }
    if (t == 0) ptr[N_NODES] = carry;
}

// fill via atomic bump on ptr2
__global__ void k_fill(const int* __restrict__ rowi, const int* __restrict__ coli,
                       int* __restrict__ ptr2, int* __restrict__ esrc) {
    int i = blockIdx.x * blockDim.x + threadIdx.x;
    int st = gridDim.x * blockDim.x;
    for (; i < N_EDGES; i += st) {
        int c = coli[i];
        int r = rowi[i];
        int p = atomicAdd(&ptr2[c], 1);
        esrc[p] = r;
    }
}

// per-block LDS histogram -> 16 global atomics per block
__global__ __launch_bounds__(256) void k_batchcnt(const int* __restrict__ batch,
                                                  int* __restrict__ cg) {
    __shared__ int h[NG];
    if (threadIdx.x < NG) h[threadIdx.x] = 0;
    __syncthreads();
    int i = blockIdx.x * blockDim.x + threadIdx.x;
    if (i < N_NODES) atomicAdd(&h[batch[i]], 1);
    __syncthreads();
    if (threadIdx.x < NG) {
        int v = h[threadIdx.x];
        if (v) atomicAdd(&cg[threadIdx.x], v);
    }
}

// ---------------- BN0 stats: block-reduced partials ----------------
__global__ __launch_bounds__(256) void k_bn0stats(const float* __restrict__ pos,
                                                  const float* __restrict__ nrm,
                                                  float* __restrict__ part /* B0*12 */) {
    float s[6] = {0, 0, 0, 0, 0, 0}, q[6] = {0, 0, 0, 0, 0, 0};
    int i = blockIdx.x * blockDim.x + threadIdx.x;
    int stp = gridDim.x * blockDim.x;
    for (; i < N_NODES; i += stp) {
        float v;
        v = pos[i * 3 + 0]; s[0] += v; q[0] += v * v;
        v = pos[i * 3 + 1]; s[1] += v; q[1] += v * v;
        v = pos[i * 3 + 2]; s[2] += v; q[2] += v * v;
        v = nrm[i * 3 + 0]; s[3] += v; q[3] += v * v;
        v = nrm[i * 3 + 1]; s[4] += v; q[4] += v * v;
        v = nrm[i * 3 + 2]; s[5] += v; q[5] += v * v;
    }
#pragma unroll
    for (int k = 0; k < 6; ++k) {
        for (int o = 32; o > 0; o >>= 1) { s[k] += __shfl_down(s[k], o); q[k] += __shfl_down(q[k], o); }
    }
    __shared__ float ls[4][12];
    const int wv = threadIdx.x >> 6;
    const int ln = threadIdx.x & 63;
    if (ln == 0) {
#pragma unroll
        for (int k = 0; k < 6; ++k) { ls[wv][k] = s[k]; ls[wv][6 + k] = q[k]; }
    }
    __syncthreads();
    if (threadIdx.x < 12)
        part[blockIdx.x * 12 + threadIdx.x] =
            ls[0][threadIdx.x] + ls[1][threadIdx.x] + ls[2][threadIdx.x] + ls[3][threadIdx.x];
}

// ---------------- fold BN0 into W1 (K=6): Wf=A*W, rvB = B^T W ----------------
__global__ void k_fold6(const float* __restrict__ W,
                        const float* __restrict__ part, float invcnt,
                        const float* __restrict__ gamma, const float* __restrict__ beta,
                        float* __restrict__ Wf, float* __restrict__ rvB) {
    __shared__ float st[12];
    int c = threadIdx.x;
    if (c < 12) {
        float a = 0.f;
        for (int b = 0; b < B0; ++b) a += part[b * 12 + c];
        st[c] = a;
    }
    __syncthreads();
    float acc = 0.f;
    for (int k = 0; k < 6; ++k) {
        float m = st[k] * invcnt;
        float var = st[6 + k] * invcnt - m * m;
        float A = gamma[k] * rsqrtf(var + BN_EPS);
        float B = beta[k] - m * A;
        float w = W[k * HID + c];
        Wf[k * HID + c] = A * w;
        acc = fmaf(B, w, acc);
    }
    rvB[c] = acc;
}

// ---------------- second-stage reduction of stats partials: PB -> PBR rows ------
__global__ __launch_bounds__(256) void k_reduce(const float* __restrict__ part,
                                                float* __restrict__ red) {
    const int b = blockIdx.x;
    const int t = threadIdx.x;
    float a0 = 0.f, a1 = 0.f;
#pragma unroll
    for (int r = 0; r < RPR; ++r) {
        const float* p = &part[(size_t)(b * RPR + r) * 512];
        a0 += p[t];
        a1 += p[t + 256];
    }
    red[(size_t)b * 512 + t] = a0;
    red[(size_t)b * 512 + 256 + t] = a1;
}

// ---------------- fold for K=256 (reduces PBR reduced partials in preamble) -----
__global__ void k_fold256(const float* __restrict__ W,
                          const float* __restrict__ red /* PBR*512 */, float invcnt,
                          const float* __restrict__ gamma, const float* __restrict__ beta,
                          u16* __restrict__ WhiT, u16* __restrict__ WloT,
                          float* __restrict__ rv) {
    __shared__ float ss[HID], sq[HID];
    int c = threadIdx.x;
    {
        float a = 0.f, b = 0.f;
#pragma unroll 4
        for (int bb = 0; bb < PBR; ++bb) {
            a += red[bb * 512 + c];
            b += red[bb * 512 + HID + c];
        }
        ss[c] = a; sq[c] = b;
    }
    __syncthreads();
    float acc = 0.f;
    for (int k = 0; k < HID; ++k) {
        float m = ss[k] * invcnt;
        float var = sq[k] * invcnt - m * m;
        float A = gamma[k] * rsqrtf(var + BN_EPS);
        float B = beta[k] - m * A;
        float w = W[k * HID + c];
        float wf = A * w;
        u16 hi = f2bf(wf);
        WhiT[c * HID + k] = hi;
        WloT[c * HID + k] = f2bf(wf - bf2f(hi));
        acc = fmaf(B, w, acc);
    }
    rv[c] = acc;
}

// ---------------- layer-1 pre-aggregation in 6-dim raw space ----------------
__global__ __launch_bounds__(256) void k_agg6(
    const float* __restrict__ pos, const float* __restrict__ nrm,
    const int* __restrict__ ptr, const int* __restrict__ esrc,
    const float* __restrict__ dinv, float* __restrict__ z) {
    const int wv = threadIdx.x >> 6;
    const int ln = threadIdx.x & 63;
    const int n = blockIdx.x * 4 + wv;
    const float dn = dinv[n];
    float z0 = 0, z1 = 0, z2 = 0, z3 = 0, z4 = 0, z5 = 0, t = 0;
    const int s_ = ptr[n], e_ = ptr[n + 1];
    for (int e = s_ + ln; e < e_; e += 64) {
        int src = esrc[e];
        float w = dn * dinv[src];
        z0 = fmaf(w, pos[src * 3 + 0], z0);
        z1 = fmaf(w, pos[src * 3 + 1], z1);
        z2 = fmaf(w, pos[src * 3 + 2], z2);
        z3 = fmaf(w, nrm[src * 3 + 0], z3);
        z4 = fmaf(w, nrm[src * 3 + 1], z4);
        z5 = fmaf(w, nrm[src * 3 + 2], z5);
        t += w;
    }
    if (ln == 0) {   // self loop
        float sl = dn * dn;
        z0 = fmaf(sl, pos[n * 3 + 0], z0);
        z1 = fmaf(sl, pos[n * 3 + 1], z1);
        z2 = fmaf(sl, pos[n * 3 + 2], z2);
        z3 = fmaf(sl, nrm[n * 3 + 0], z3);
        z4 = fmaf(sl, nrm[n * 3 + 1], z4);
        z5 = fmaf(sl, nrm[n * 3 + 2], z5);
        t += sl;
    }
#pragma unroll
    for (int o = 1; o < 64; o <<= 1) {
        z0 += __shfl_xor(z0, o); z1 += __shfl_xor(z1, o); z2 += __shfl_xor(z2, o);
        z3 += __shfl_xor(z3, o); z4 += __shfl_xor(z4, o); z5 += __shfl_xor(z5, o);
        t  += __shfl_xor(t, o);
    }
    if (ln == 0) {
        *reinterpret_cast<f32x4*>(&z[n * 8])     = f32x4{z0, z1, z2, z3};
        *reinterpret_cast<f32x4*>(&z[n * 8 + 4]) = f32x4{z4, z5, t, 0.f};
    }
}

// ---------------- layer-1: y1 = relu(z6 @ Wf + s*rvB + b1) -> bf16 ----------------
__global__ __launch_bounds__(256) void k_gemm1b(
    const float* __restrict__ z, const float* __restrict__ Wf,
    const float* __restrict__ rvB, const float* __restrict__ b1,
    u16* __restrict__ out) {
    const int c = threadIdx.x;
    float w0 = Wf[0 * HID + c], w1 = Wf[1 * HID + c], w2 = Wf[2 * HID + c];
    float w3 = Wf[3 * HID + c], w4 = Wf[4 * HID + c], w5 = Wf[5 * HID + c];
    const float rvc = rvB[c], bc = b1[c];
    for (int n = blockIdx.x; n < N_NODES; n += gridDim.x) {
        float x0 = z[n * 8 + 0], x1 = z[n * 8 + 1], x2 = z[n * 8 + 2];
        float x3 = z[n * 8 + 3], x4 = z[n * 8 + 4], x5 = z[n * 8 + 5];
        float s  = z[n * 8 + 6];
        float acc = fmaf(s, rvc, bc);
        acc = fmaf(x0, w0, acc); acc = fmaf(x1, w1, acc); acc = fmaf(x2, w2, acc);
        acc = fmaf(x3, w3, acc); acc = fmaf(x4, w4, acc); acc = fmaf(x5, w5, acc);
        out[(size_t)n * HID + c] = f2bf(fmaxf(acc, 0.f));
    }
}

// ---------------- MFMA GEMM: [N,256](bf16) @ (WhiT+WloT) + rv -> bf16 ----------------
__global__ __launch_bounds__(256) void k_gemm_mfma(
    const u16* __restrict__ X, const u16* __restrict__ WhiT,
    const u16* __restrict__ WloT, const float* __restrict__ rv,
    u16* __restrict__ out) {
    const int tid = threadIdx.x;
    const int wv = tid >> 6;
    const int ln = tid & 63;
    const int row0 = blockIdx.x * 64;
    const int lr = ln & 15;
    const int lk = (ln >> 4) * 8;
    const int wcol0 = wv * 64;

    f32x4 acc[4][4] = {};
    for (int kk = 0; kk < HID; kk += 32) {
        bf16x8 a[4], bh[4], bl[4];
#pragma unroll
        for (int i = 0; i < 4; ++i) {
            int r = row0 + i * 16 + lr;
            if (r >= N_NODES) r = N_NODES - 1;
            a[i] = *reinterpret_cast<const bf16x8*>(&X[(size_t)r * HID + kk + lk]);
        }
#pragma unroll
        for (int c = 0; c < 4; ++c) {
            int col = wcol0 + c * 16 + lr;
            bh[c] = *reinterpret_cast<const bf16x8*>(&WhiT[(size_t)col * HID + kk + lk]);
            bl[c] = *reinterpret_cast<const bf16x8*>(&WloT[(size_t)col * HID + kk + lk]);
        }
#pragma unroll
        for (int i = 0; i < 4; ++i)
#pragma unroll
            for (int c = 0; c < 4; ++c) {
                acc[i][c] = __builtin_amdgcn_mfma_f32_16x16x32_bf16(a[i], bh[c], acc[i][c], 0, 0, 0);
                acc[i][c] = __builtin_amdgcn_mfma_f32_16x16x32_bf16(a[i], bl[c], acc[i][c], 0, 0, 0);
            }
    }
    const int crow = (ln >> 4) * 4;
#pragma unroll
    for (int c = 0; c < 4; ++c) {
        int col = wcol0 + c * 16 + lr;
        float rvc = rv[col];
#pragma unroll
        for (int i = 0; i < 4; ++i) {
#pragma unroll
            for (int rg = 0; rg < 4; ++rg) {
                int r = row0 + i * 16 + crow + rg;
                if (r < N_NODES)
                    out[(size_t)r * HID + col] = f2bf(acc[i][c][rg] + rvc);
            }
        }
    }
}

// -------- XCD-sliced aggregation: y = relu(S.xw + bias), slice = bid & 7 --------
// wave = one (node, slice of 32 channels); lanes = 32 ch x 2 edge-parities.
// Under round-robin workgroup->XCD dispatch, slice s stays on XCD s: per-XCD
// gather working set drops 51.2MB -> 6.4MB (~L2-resident). 64B/line per edge.
__global__ __launch_bounds__(256) void k_agg_s(
    const u16* __restrict__ xw, const int* __restrict__ ptr,
    const int* __restrict__ esrc, const float* __restrict__ dinv,
    const float* __restrict__ bias, u16* __restrict__ y) {
    const int wv = threadIdx.x >> 6;
    const int ln = threadIdx.x & 63;
    const int slice = blockIdx.x & 7;
    const int n = (blockIdx.x >> 3) * 4 + wv;
    const int ch = slice * 32 + (ln & 31);
    const int epar = ln >> 5;
    const float dn = dinv[n];
    const int s = ptr[n], e = ptr[n + 1];
    float a = 0.f;
    for (int i = s + epar; i < e; i += 2) {
        int src = esrc[i];
        float w = dinv[src] * dn;
        a = fmaf(w, bf2f(xw[(size_t)src * HID + ch]), a);
    }
    a += __shfl_xor(a, 32);   // combine edge parities; both halves hold total
    if (ln < 32) {
        float sl = dn * dn;
        a = fmaf(sl, bf2f(xw[(size_t)n * HID + ch]), a);
        a = fmaxf(a + bias[ch], 0.f);
        y[(size_t)n * HID + ch] = f2bf(a);
    }
}

// ---------------- per-channel stats partials: contiguous chunks, PB blocks ------
__global__ __launch_bounds__(256) void k_stats(const u16* __restrict__ y,
                                               float* __restrict__ part /* PB*512 */) {
    const int c = threadIdx.x;
    const int n0 = blockIdx.x * SROWS;
    const int n1 = (n0 + SROWS < N_NODES) ? n0 + SROWS : N_NODES;
    float s = 0.f, q = 0.f;
    int n = n0;
    for (; n + 3 < n1; n += 4) {
        float v0 = bf2f(y[(size_t)n * HID + c]);
        float v1 = bf2f(y[(size_t)(n + 1) * HID + c]);
        float v2 = bf2f(y[(size_t)(n + 2) * HID + c]);
        float v3 = bf2f(y[(size_t)(n + 3) * HID + c]);
        s += v0 + v1 + v2 + v3;
        q = fmaf(v0, v0, q); q = fmaf(v1, v1, q);
        q = fmaf(v2, v2, q); q = fmaf(v3, v3, q);
    }
    for (; n < n1; ++n) {
        float v = bf2f(y[(size_t)n * HID + c]);
        s += v;
        q = fmaf(v, v, q);
    }
    part[blockIdx.x * 512 + c] = s;
    part[blockIdx.x * 512 + HID + c] = q;
}

// ---------------- stats + pooled sums fused (batch sorted) ----------------
__global__ __launch_bounds__(256) void k_statspool(const u16* __restrict__ y,
                                                   const int* __restrict__ batch,
                                                   float* __restrict__ part,
                                                   float* __restrict__ ps) {
    const int c = threadIdx.x;
    const int n0 = blockIdx.x * SROWS;
    const int n1 = (n0 + SROWS < N_NODES) ? n0 + SROWS : N_NODES;
    float s = 0.f, q = 0.f;
    if (n0 < N_NODES) {
        int cur = batch[n0];
        float acc = 0.f;
        for (int n = n0; n < n1; ++n) {
            float v = bf2f(y[(size_t)n * HID + c]);
            int g = batch[n];
            if (g != cur) {
                atomicAdd(&ps[cur * HID + c], acc);
                acc = 0.f;
                cur = g;
            }
            s += v;
            q = fmaf(v, v, q);
            acc += v;
        }
        atomicAdd(&ps[cur * HID + c], acc);
    }
    part[blockIdx.x * 512 + c] = s;
    part[blockIdx.x * 512 + HID + c] = q;
}

// ---------------- finalize: BN4 affine on pooled sums (reduces PBR partials) ----
__global__ void k_final(const float* __restrict__ ps, const int* __restrict__ cg,
                        const float* __restrict__ red, const float* __restrict__ gamma,
                        const float* __restrict__ beta, float* __restrict__ out) {
    __shared__ float ss[HID], sq[HID];
    const int c = threadIdx.x;
    {
        float a = 0.f, b = 0.f;
#pragma unroll 4
        for (int bb = 0; bb < PBR; ++bb) {
            a += red[bb * 512 + c];
            b += red[bb * 512 + HID + c];
        }
        ss[c] = a; sq[c] = b;
    }
    __syncthreads();
    const float invn = 1.0f / (float)N_NODES;
    float m = ss[c] * invn;
    float var = sq[c] * invn - m * m;
    float A = gamma[c] * rsqrtf(var + BN_EPS);
    float B = beta[c] - m * A;
    for (int g = 0; g < NG; ++g) {
        float cn = (float)cg[g];
        float val = (A * ps[g * HID + c] + cn * B) / fmaxf(cn, 1.0f);
        out[g * HID + c] = val;
    }
}

extern "C" void kernel_launch(void* const* d_in, const int* in_sizes, int n_in,
                              void* d_out, int out_size, void* d_ws, size_t ws_size,
                              hipStream_t stream) {
    const float* pos   = (const float*)d_in[0];
    const float* nrm   = (const float*)d_in[1];
    const int*   ei    = (const int*)d_in[2];
    const int*   batch = (const int*)d_in[3];
    const float* bn0g  = (const float*)d_in[4];
    const float* bn0b  = (const float*)d_in[5];
    const float* W[4]   = {(const float*)d_in[6],  (const float*)d_in[10], (const float*)d_in[14], (const float*)d_in[18]};
    const float* bb[4]  = {(const float*)d_in[7],  (const float*)d_in[11], (const float*)d_in[15], (const float*)d_in[19]};
    const float* bg[4]  = {(const float*)d_in[8],  (const float*)d_in[12], (const float*)d_in[16], (const float*)d_in[20]};
    const float* bbt[4] = {(const float*)d_in[9],  (const float*)d_in[13], (const float*)d_in[17], (const float*)d_in[21]};

    char* wp = (char*)d_ws;
    auto alloc = [&](size_t bytes) {
        char* p = wp;
        wp += (bytes + 255) & ~(size_t)255;
        return p;
    };
    float* dinv  = (float*)alloc((size_t)N_NODES * 4);
    int*   cnt   = (int*)  alloc((size_t)N_NODES * 4);
    int*   ptr   = (int*)  alloc((size_t)(N_NODES + 1) * 4);
    int*   ptr2  = (int*)  alloc((size_t)N_NODES * 4);
    int*   esrc  = (int*)  alloc((size_t)N_EDGES * 4);
    u16*   bufA  = (u16*)  alloc((size_t)N_NODES * HID * 2);
    u16*   bufB  = (u16*)  alloc((size_t)N_NODES * HID * 2);
    float* zbuf  = (float*)alloc((size_t)N_NODES * 8 * 4);
    float* part0 = (float*)alloc((size_t)B0 * 12 * 4);
    float* partL = (float*)alloc((size_t)PB * 512 * 4);
    float* red   = (float*)alloc((size_t)PBR * 512 * 4);
    float* Wf1   = (float*)alloc((size_t)6 * HID * 4);
    u16*   WhiT  = (u16*)  alloc((size_t)HID * HID * 2);
    u16*   WloT  = (u16*)  alloc((size_t)HID * HID * 2);
    float* rv    = (float*)alloc(HID * 4);
    float* ps    = (float*)alloc(NG * HID * 4);
    int*   cg    = (int*)  alloc(NG * 4);
    (void)ws_size; (void)in_sizes; (void)n_in; (void)out_size;

    const int* rowi = ei;
    const int* coli = ei + N_EDGES;

    hipMemsetAsync(cnt, 0, (size_t)N_NODES * 4, stream);
    hipMemsetAsync(ps, 0, NG * HID * 4, stream);
    hipMemsetAsync(cg, 0, NG * 4, stream);

    // CSR + norms
    k_count<<<2048, 256, 0, stream>>>(coli, cnt);
    k_scan<<<1, 1024, 0, stream>>>(cnt, ptr, ptr2, dinv);
    k_fill<<<2048, 256, 0, stream>>>(rowi, coli, ptr2, esrc);
    k_batchcnt<<<(N_NODES + 255) / 256, 256, 0, stream>>>(batch, cg);

    // layer 1: aggregate in 6-dim raw space, then tiny GEMM with BN0 folded
    k_bn0stats<<<B0, 256, 0, stream>>>(pos, nrm, part0);
    k_fold6<<<1, 256, 0, stream>>>(W[0], part0, 1.0f / (float)N_NODES, bn0g, bn0b, Wf1, rv);
    k_agg6<<<N_NODES / 4, 256, 0, stream>>>(pos, nrm, ptr, esrc, dinv, zbuf);
    k_gemm1b<<<2048, 256, 0, stream>>>(zbuf, Wf1, rv, bb[0], bufA);   // bufA = a_1

    // layers 2..4: stats -> reduce -> fold BN_l into W_{l+1} -> MFMA gemm -> aggregate
    for (int l = 0; l < 3; ++l) {
        k_stats<<<PB, 256, 0, stream>>>(bufA, partL);
        k_reduce<<<PBR, 256, 0, stream>>>(partL, red);
        k_fold256<<<1, 256, 0, stream>>>(W[l + 1], red, 1.0f / (float)N_NODES,
                                         bg[l], bbt[l], WhiT, WloT, rv);
        k_gemm_mfma<<<(N_NODES + 63) / 64, 256, 0, stream>>>(bufA, WhiT, WloT, rv, bufB);
        k_agg_s<<<(N_NODES / 4) * 8, 256, 0, stream>>>(bufB, ptr, esrc, dinv, bb[l + 1], bufA);
    }

    // final: fused stats+pool, then BN4 applied analytically on pooled sums
    k_statspool<<<PB, 256, 0, stream>>>(bufA, batch, partL, ps);
    k_reduce<<<PBR, 256, 0, stream>>>(partL, red);
    k_final<<<1, 256, 0, stream>>>(ps, cg, red, bg[3], bbt[3], (float*)d_out);
}

// Round 10
// 1721.676 us; speedup vs baseline: 2.6646x; 2.6646x over previous
//
#include <hip/hip_runtime.h>
#include <hip/hip_bf16.h>
#include <cstdint>

#define N_NODES 100000
#define NPAD    100032   // padded row count (multiple of 64)
#define N_EDGES 3200000
#define HID 256
#define NG 16
#define BN_EPS 1e-5f
#define B0 120       // bn0stats partial blocks
#define PB 1024      // stats partial blocks
#define SROWS ((N_NODES + PB - 1) / PB)   // 98 rows per stats block
#define PBR 128      // second-stage reduction blocks
#define RPR (PB / PBR)                    // 8 partial rows per reduce block
#define FPART 12500  // k_fill column-partition width (8 * 12500 = 100000)

typedef unsigned short u16;
using bf16x8 = __attribute__((ext_vector_type(8))) short;
using f32x4  = __attribute__((ext_vector_type(4))) float;

__device__ __forceinline__ float bf2f(u16 b) {
    return __uint_as_float(((unsigned)b) << 16);
}
__device__ __forceinline__ u16 f2bf(float f) {
    unsigned u = __float_as_uint(f);
    unsigned r = (u + 0x7FFFu + ((u >> 16) & 1u)) >> 16;
    return (u16)r;
}
__device__ __forceinline__ float4 ld_bf16x4(const u16* p) {
    ushort4 u = *reinterpret_cast<const ushort4*>(p);
    float4 f;
    f.x = bf2f(u.x); f.y = bf2f(u.y); f.z = bf2f(u.z); f.w = bf2f(u.w);
    return f;
}

// ---------------- CSR build ----------------
__global__ void k_count(const int* __restrict__ coli, int* __restrict__ cnt) {
    int i = blockIdx.x * blockDim.x + threadIdx.x;
    int st = gridDim.x * blockDim.x;
    for (; i < N_EDGES; i += st) atomicAdd(&cnt[coli[i]], 1);
}

// 1024-thread single-block scan (wave-shuffle) + fused dinv; writes ptr AND ptr2
__global__ void k_scan(const int* __restrict__ cnt, int* __restrict__ ptr,
                       int* __restrict__ ptr2, float* __restrict__ dinv) {
    __shared__ int wsum[16];
    const int t = threadIdx.x;
    const int wv = t >> 6;
    const int ln = t & 63;
    int carry = 0;
    for (int base = 0; base < N_NODES; base += 4096) {
        int idx = base + t * 4;
        int v0 = 0, v1 = 0, v2 = 0, v3 = 0;
        if (idx + 3 < N_NODES) {
            int4 q = *reinterpret_cast<const int4*>(&cnt[idx]);
            v0 = q.x; v1 = q.y; v2 = q.z; v3 = q.w;
        } else {
            if (idx + 0 < N_NODES) v0 = cnt[idx + 0];
            if (idx + 1 < N_NODES) v1 = cnt[idx + 1];
            if (idx + 2 < N_NODES) v2 = cnt[idx + 2];
        }
        if (idx + 0 < N_NODES) dinv[idx + 0] = rsqrtf((float)v0 + 1.0f);
        if (idx + 1 < N_NODES) dinv[idx + 1] = rsqrtf((float)v1 + 1.0f);
        if (idx + 2 < N_NODES) dinv[idx + 2] = rsqrtf((float)v2 + 1.0f);
        if (idx + 3 < N_NODES) dinv[idx + 3] = rsqrtf((float)v3 + 1.0f);
        int s = v0 + v1 + v2 + v3;
        int sc = s;
        for (int off = 1; off < 64; off <<= 1) {
            int u = __shfl_up(sc, off);
            if (ln >= off) sc += u;
        }
        if (ln == 63) wsum[wv] = sc;
        __syncthreads();
        if (wv == 0 && ln < 16) {
            int a = wsum[ln];
            for (int off = 1; off < 16; off <<= 1) {
                int u = __shfl_up(a, off, 16);
                if (ln >= off) a += u;
            }
            wsum[ln] = a;
        }
        __syncthreads();
        int total = wsum[15];
        int excl = carry + (wv ? wsum[wv - 1] : 0) + sc - s;
        if (idx + 0 < N_NODES) { ptr[idx + 0] = excl; ptr2[idx + 0] = excl; } excl += v0;
        if (idx + 1 < N_NODES) { ptr[idx + 1] = excl; ptr2[idx + 1] = excl; } excl += v1;
        if (idx + 2 < N_NODES) { ptr[idx + 2] = excl; ptr2[idx + 2] = excl; } excl += v2;
        if (idx + 3 < N_NODES) { ptr[idx + 3] = excl; ptr2[idx + 3] = excl; }
        __syncthreads();
        carry += total;
    }
    if (t == 0) ptr[N_NODES] = carry;
}

// partitioned fill: this pass only handles cols in [lo, lo+FPART).
// Active scatter region per pass = 1.6MB -> dirty lines fill before eviction.
__global__ void k_fillp(const int* __restrict__ rowi, const int* __restrict__ coli,
                        int* __restrict__ ptr2, int* __restrict__ esrc, int lo) {
    int i = blockIdx.x * blockDim.x + threadIdx.x;
    int st = gridDim.x * blockDim.x;
    const int hi = lo + FPART;
    for (; i < N_EDGES; i += st) {
        int c = coli[i];
        if (c >= lo && c < hi) {
            int p = atomicAdd(&ptr2[c], 1);
            esrc[p] = rowi[i];
        }
    }
}

// per-block LDS histogram -> 16 global atomics per block
__global__ __launch_bounds__(256) void k_batchcnt(const int* __restrict__ batch,
                                                  int* __restrict__ cg) {
    __shared__ int h[NG];
    if (threadIdx.x < NG) h[threadIdx.x] = 0;
    __syncthreads();
    int i = blockIdx.x * blockDim.x + threadIdx.x;
    if (i < N_NODES) atomicAdd(&h[batch[i]], 1);
    __syncthreads();
    if (threadIdx.x < NG) {
        int v = h[threadIdx.x];
        if (v) atomicAdd(&cg[threadIdx.x], v);
    }
}

// ---------------- BN0 stats: block-reduced partials ----------------
__global__ __launch_bounds__(256) void k_bn0stats(const float* __restrict__ pos,
                                                  const float* __restrict__ nrm,
                                                  float* __restrict__ part /* B0*12 */) {
    float s[6] = {0, 0, 0, 0, 0, 0}, q[6] = {0, 0, 0, 0, 0, 0};
    int i = blockIdx.x * blockDim.x + threadIdx.x;
    int stp = gridDim.x * blockDim.x;
    for (; i < N_NODES; i += stp) {
        float v;
        v = pos[i * 3 + 0]; s[0] += v; q[0] += v * v;
        v = pos[i * 3 + 1]; s[1] += v; q[1] += v * v;
        v = pos[i * 3 + 2]; s[2] += v; q[2] += v * v;
        v = nrm[i * 3 + 0]; s[3] += v; q[3] += v * v;
        v = nrm[i * 3 + 1]; s[4] += v; q[4] += v * v;
        v = nrm[i * 3 + 2]; s[5] += v; q[5] += v * v;
    }
#pragma unroll
    for (int k = 0; k < 6; ++k) {
        for (int o = 32; o > 0; o >>= 1) { s[k] += __shfl_down(s[k], o); q[k] += __shfl_down(q[k], o); }
    }
    __shared__ float ls[4][12];
    const int wv = threadIdx.x >> 6;
    const int ln = threadIdx.x & 63;
    if (ln == 0) {
#pragma unroll
        for (int k = 0; k < 6; ++k) { ls[wv][k] = s[k]; ls[wv][6 + k] = q[k]; }
    }
    __syncthreads();
    if (threadIdx.x < 12)
        part[blockIdx.x * 12 + threadIdx.x] =
            ls[0][threadIdx.x] + ls[1][threadIdx.x] + ls[2][threadIdx.x] + ls[3][threadIdx.x];
}

// ---------------- fold BN0 into W1 (K=6): Wf=A*W, rvB = B^T W ----------------
__global__ void k_fold6(const float* __restrict__ W,
                        const float* __restrict__ part, float invcnt,
                        const float* __restrict__ gamma, const float* __restrict__ beta,
                        float* __restrict__ Wf, float* __restrict__ rvB) {
    __shared__ float st[12];
    int c = threadIdx.x;
    if (c < 12) {
        float a = 0.f;
        for (int b = 0; b < B0; ++b) a += part[b * 12 + c];
        st[c] = a;
    }
    __syncthreads();
    float acc = 0.f;
    for (int k = 0; k < 6; ++k) {
        float m = st[k] * invcnt;
        float var = st[6 + k] * invcnt - m * m;
        float A = gamma[k] * rsqrtf(var + BN_EPS);
        float B = beta[k] - m * A;
        float w = W[k * HID + c];
        Wf[k * HID + c] = A * w;
        acc = fmaf(B, w, acc);
    }
    rvB[c] = acc;
}

// ---------------- second-stage reduction of stats partials: PB -> PBR rows ------
__global__ __launch_bounds__(256) void k_reduce(const float* __restrict__ part,
                                                float* __restrict__ red) {
    const int b = blockIdx.x;
    const int t = threadIdx.x;
    float a0 = 0.f, a1 = 0.f;
#pragma unroll
    for (int r = 0; r < RPR; ++r) {
        const float* p = &part[(size_t)(b * RPR + r) * 512];
        a0 += p[t];
        a1 += p[t + 256];
    }
    red[(size_t)b * 512 + t] = a0;
    red[(size_t)b * 512 + 256 + t] = a1;
}

// ---------------- fold for K=256 (reduces PBR reduced partials in preamble) -----
__global__ void k_fold256(const float* __restrict__ W,
                          const float* __restrict__ red /* PBR*512 */, float invcnt,
                          const float* __restrict__ gamma, const float* __restrict__ beta,
                          u16* __restrict__ WhiT, u16* __restrict__ WloT,
                          float* __restrict__ rv) {
    __shared__ float ss[HID], sq[HID];
    int c = threadIdx.x;
    {
        float a = 0.f, b = 0.f;
#pragma unroll 4
        for (int bb = 0; bb < PBR; ++bb) {
            a += red[bb * 512 + c];
            b += red[bb * 512 + HID + c];
        }
        ss[c] = a; sq[c] = b;
    }
    __syncthreads();
    float acc = 0.f;
    for (int k = 0; k < HID; ++k) {
        float m = ss[k] * invcnt;
        float var = sq[k] * invcnt - m * m;
        float A = gamma[k] * rsqrtf(var + BN_EPS);
        float B = beta[k] - m * A;
        float w = W[k * HID + c];
        float wf = A * w;
        u16 hi = f2bf(wf);
        WhiT[c * HID + k] = hi;
        WloT[c * HID + k] = f2bf(wf - bf2f(hi));
        acc = fmaf(B, w, acc);
    }
    rv[c] = acc;
}

// ---------------- layer-1 pre-aggregation in 6-dim raw space ----------------
__global__ __launch_bounds__(256) void k_agg6(
    const float* __restrict__ pos, const float* __restrict__ nrm,
    const int* __restrict__ ptr, const int* __restrict__ esrc,
    const float* __restrict__ dinv, float* __restrict__ z) {
    const int wv = threadIdx.x >> 6;
    const int ln = threadIdx.x & 63;
    const int n = blockIdx.x * 4 + wv;
    const float dn = dinv[n];
    float z0 = 0, z1 = 0, z2 = 0, z3 = 0, z4 = 0, z5 = 0, t = 0;
    const int s_ = ptr[n], e_ = ptr[n + 1];
    for (int e = s_ + ln; e < e_; e += 64) {
        int src = esrc[e];
        float w = dn * dinv[src];
        z0 = fmaf(w, pos[src * 3 + 0], z0);
        z1 = fmaf(w, pos[src * 3 + 1], z1);
        z2 = fmaf(w, pos[src * 3 + 2], z2);
        z3 = fmaf(w, nrm[src * 3 + 0], z3);
        z4 = fmaf(w, nrm[src * 3 + 1], z4);
        z5 = fmaf(w, nrm[src * 3 + 2], z5);
        t += w;
    }
    if (ln == 0) {   // self loop
        float sl = dn * dn;
        z0 = fmaf(sl, pos[n * 3 + 0], z0);
        z1 = fmaf(sl, pos[n * 3 + 1], z1);
        z2 = fmaf(sl, pos[n * 3 + 2], z2);
        z3 = fmaf(sl, nrm[n * 3 + 0], z3);
        z4 = fmaf(sl, nrm[n * 3 + 1], z4);
        z5 = fmaf(sl, nrm[n * 3 + 2], z5);
        t += sl;
    }
#pragma unroll
    for (int o = 1; o < 64; o <<= 1) {
        z0 += __shfl_xor(z0, o); z1 += __shfl_xor(z1, o); z2 += __shfl_xor(z2, o);
        z3 += __shfl_xor(z3, o); z4 += __shfl_xor(z4, o); z5 += __shfl_xor(z5, o);
        t  += __shfl_xor(t, o);
    }
    if (ln == 0) {
        *reinterpret_cast<f32x4*>(&z[n * 8])     = f32x4{z0, z1, z2, z3};
        *reinterpret_cast<f32x4*>(&z[n * 8 + 4]) = f32x4{z4, z5, t, 0.f};
    }
}

// ---------------- layer-1: y1 = relu(z6 @ Wf + s*rvB + b1) -> bf16 ----------------
__global__ __launch_bounds__(256) void k_gemm1b(
    const float* __restrict__ z, const float* __restrict__ Wf,
    const float* __restrict__ rvB, const float* __restrict__ b1,
    u16* __restrict__ out) {
    const int c = threadIdx.x;
    float w0 = Wf[0 * HID + c], w1 = Wf[1 * HID + c], w2 = Wf[2 * HID + c];
    float w3 = Wf[3 * HID + c], w4 = Wf[4 * HID + c], w5 = Wf[5 * HID + c];
    const float rvc = rvB[c], bc = b1[c];
    for (int n = blockIdx.x; n < N_NODES; n += gridDim.x) {
        float x0 = z[n * 8 + 0], x1 = z[n * 8 + 1], x2 = z[n * 8 + 2];
        float x3 = z[n * 8 + 3], x4 = z[n * 8 + 4], x5 = z[n * 8 + 5];
        float s  = z[n * 8 + 6];
        float acc = fmaf(s, rvc, bc);
        acc = fmaf(x0, w0, acc); acc = fmaf(x1, w1, acc); acc = fmaf(x2, w2, acc);
        acc = fmaf(x3, w3, acc); acc = fmaf(x4, w4, acc); acc = fmaf(x5, w5, acc);
        out[(size_t)n * HID + c] = f2bf(fmaxf(acc, 0.f));
    }
}

// ---------------- MFMA GEMM on padded [NPAD,256]: no bounds checks ----------------
__global__ __launch_bounds__(256) void k_gemm_mfma(
    const u16* __restrict__ X, const u16* __restrict__ WhiT,
    const u16* __restrict__ WloT, const float* __restrict__ rv,
    u16* __restrict__ out) {
    const int tid = threadIdx.x;
    const int wv = tid >> 6;
    const int ln = tid & 63;
    const int row0 = blockIdx.x * 64;
    const int lr = ln & 15;
    const int lk = (ln >> 4) * 8;
    const int wcol0 = wv * 64;

    f32x4 acc[4][4] = {};
    for (int kk = 0; kk < HID; kk += 32) {
        bf16x8 a[4], bh[4], bl[4];
#pragma unroll
        for (int i = 0; i < 4; ++i) {
            int r = row0 + i * 16 + lr;
            a[i] = *reinterpret_cast<const bf16x8*>(&X[(size_t)r * HID + kk + lk]);
        }
#pragma unroll
        for (int c = 0; c < 4; ++c) {
            int col = wcol0 + c * 16 + lr;
            bh[c] = *reinterpret_cast<const bf16x8*>(&WhiT[(size_t)col * HID + kk + lk]);
            bl[c] = *reinterpret_cast<const bf16x8*>(&WloT[(size_t)col * HID + kk + lk]);
        }
#pragma unroll
        for (int i = 0; i < 4; ++i)
#pragma unroll
            for (int c = 0; c < 4; ++c) {
                acc[i][c] = __builtin_amdgcn_mfma_f32_16x16x32_bf16(a[i], bh[c], acc[i][c], 0, 0, 0);
                acc[i][c] = __builtin_amdgcn_mfma_f32_16x16x32_bf16(a[i], bl[c], acc[i][c], 0, 0, 0);
            }
    }
    const int crow = (ln >> 4) * 4;
#pragma unroll
    for (int c = 0; c < 4; ++c) {
        int col = wcol0 + c * 16 + lr;
        float rvc = rv[col];
#pragma unroll
        for (int i = 0; i < 4; ++i) {
#pragma unroll
            for (int rg = 0; rg < 4; ++rg) {
                int r = row0 + i * 16 + crow + rg;
                out[(size_t)r * HID + col] = f2bf(acc[i][c][rg] + rvc);
            }
        }
    }
}

// ---------------- aggregation: y = relu(S.xw + bias) ----------------
__global__ __launch_bounds__(256) void k_agg(
    const u16* __restrict__ xw, const int* __restrict__ ptr,
    const int* __restrict__ esrc, const float* __restrict__ dinv,
    const float* __restrict__ bias, u16* __restrict__ y) {
    const int wv = threadIdx.x >> 6;
    const int ln = threadIdx.x & 63;
    const int n = blockIdx.x * 4 + wv;
    const float dn = dinv[n];
    const size_t base = (size_t)n * HID + ln * 4;
    float4 v = ld_bf16x4(&xw[base]);
    const float sl = dn * dn;
    float a0 = v.x * sl, a1 = v.y * sl, a2 = v.z * sl, a3 = v.w * sl;
    const int s = ptr[n], e = ptr[n + 1];
#pragma unroll 2
    for (int i = s; i < e; ++i) {
        int src = esrc[i];
        float w = dinv[src] * dn;
        float4 u = ld_bf16x4(&xw[(size_t)src * HID + ln * 4]);
        a0 = fmaf(w, u.x, a0);
        a1 = fmaf(w, u.y, a1);
        a2 = fmaf(w, u.z, a2);
        a3 = fmaf(w, u.w, a3);
    }
    float4 b = *reinterpret_cast<const float4*>(&bias[ln * 4]);
    a0 = fmaxf(a0 + b.x, 0.f);
    a1 = fmaxf(a1 + b.y, 0.f);
    a2 = fmaxf(a2 + b.z, 0.f);
    a3 = fmaxf(a3 + b.w, 0.f);
    ushort4 o;
    o.x = f2bf(a0); o.y = f2bf(a1); o.z = f2bf(a2); o.w = f2bf(a3);
    *reinterpret_cast<ushort4*>(&y[base]) = o;
}

// ------- per-channel stats partials: vectorized (4 row-lanes x 64 ch-quads) ------
__global__ __launch_bounds__(256) void k_stats(const u16* __restrict__ y,
                                               float* __restrict__ part /* PB*512 */) {
    const int t = threadIdx.x;
    const int cl = t & 63;          // channel quad: channels cl*4 .. cl*4+3
    const int rp = t >> 6;          // row parity 0..3
    const int n0 = blockIdx.x * SROWS;
    const int n1 = (n0 + SROWS < N_NODES) ? n0 + SROWS : N_NODES;
    float s0 = 0, s1 = 0, s2 = 0, s3 = 0, q0 = 0, q1 = 0, q2 = 0, q3 = 0;
    for (int n = n0 + rp; n < n1; n += 4) {
        float4 v = ld_bf16x4(&y[(size_t)n * HID + cl * 4]);
        s0 += v.x; q0 = fmaf(v.x, v.x, q0);
        s1 += v.y; q1 = fmaf(v.y, v.y, q1);
        s2 += v.z; q2 = fmaf(v.z, v.z, q2);
        s3 += v.w; q3 = fmaf(v.w, v.w, q3);
    }
    __shared__ float sh[4 * 512];
    float* shr = &sh[rp * 512];
    shr[cl * 4 + 0] = s0; shr[cl * 4 + 1] = s1;
    shr[cl * 4 + 2] = s2; shr[cl * 4 + 3] = s3;
    shr[256 + cl * 4 + 0] = q0; shr[256 + cl * 4 + 1] = q1;
    shr[256 + cl * 4 + 2] = q2; shr[256 + cl * 4 + 3] = q3;
    __syncthreads();
    float a = sh[t] + sh[512 + t] + sh[1024 + t] + sh[1536 + t];
    float b = sh[256 + t] + sh[768 + t] + sh[1280 + t] + sh[1792 + t];
    part[blockIdx.x * 512 + t] = a;
    part[blockIdx.x * 512 + 256 + t] = b;
}

// ---------------- stats + pooled sums fused (batch sorted) ----------------
__global__ __launch_bounds__(256) void k_statspool(const u16* __restrict__ y,
                                                   const int* __restrict__ batch,
                                                   float* __restrict__ part,
                                                   float* __restrict__ ps) {
    const int c = threadIdx.x;
    const int n0 = blockIdx.x * SROWS;
    const int n1 = (n0 + SROWS < N_NODES) ? n0 + SROWS : N_NODES;
    float s = 0.f, q = 0.f;
    if (n0 < N_NODES) {
        int cur = batch[n0];
        float acc = 0.f;
        for (int n = n0; n < n1; ++n) {
            float v = bf2f(y[(size_t)n * HID + c]);
            int g = batch[n];
            if (g != cur) {
                atomicAdd(&ps[cur * HID + c], acc);
                acc = 0.f;
                cur = g;
            }
            s += v;
            q = fmaf(v, v, q);
            acc += v;
        }
        atomicAdd(&ps[cur * HID + c], acc);
    }
    part[blockIdx.x * 512 + c] = s;
    part[blockIdx.x * 512 + HID + c] = q;
}

// ---------------- finalize: BN4 affine on pooled sums (reduces PBR partials) ----
__global__ void k_final(const float* __restrict__ ps, const int* __restrict__ cg,
                        const float* __restrict__ red, const float* __restrict__ gamma,
                        const float* __restrict__ beta, float* __restrict__ out) {
    __shared__ float ss[HID], sq[HID];
    const int c = threadIdx.x;
    {
        float a = 0.f, b = 0.f;
#pragma unroll 4
        for (int bb = 0; bb < PBR; ++bb) {
            a += red[bb * 512 + c];
            b += red[bb * 512 + HID + c];
        }
        ss[c] = a; sq[c] = b;
    }
    __syncthreads();
    const float invn = 1.0f / (float)N_NODES;
    float m = ss[c] * invn;
    float var = sq[c] * invn - m * m;
    float A = gamma[c] * rsqrtf(var + BN_EPS);
    float B = beta[c] - m * A;
    for (int g = 0; g < NG; ++g) {
        float cn = (float)cg[g];
        float val = (A * ps[g * HID + c] + cn * B) / fmaxf(cn, 1.0f);
        out[g * HID + c] = val;
    }
}

extern "C" void kernel_launch(void* const* d_in, const int* in_sizes, int n_in,
                              void* d_out, int out_size, void* d_ws, size_t ws_size,
                              hipStream_t stream) {
    const float* pos   = (const float*)d_in[0];
    const float* nrm   = (const float*)d_in[1];
    const int*   ei    = (const int*)d_in[2];
    const int*   batch = (const int*)d_in[3];
    const float* bn0g  = (const float*)d_in[4];
    const float* bn0b  = (const float*)d_in[5];
    const float* W[4]   = {(const float*)d_in[6],  (const float*)d_in[10], (const float*)d_in[14], (const float*)d_in[18]};
    const float* bb[4]  = {(const float*)d_in[7],  (const float*)d_in[11], (const float*)d_in[15], (const float*)d_in[19]};
    const float* bg[4]  = {(const float*)d_in[8],  (const float*)d_in[12], (const float*)d_in[16], (const float*)d_in[20]};
    const float* bbt[4] = {(const float*)d_in[9],  (const float*)d_in[13], (const float*)d_in[17], (const float*)d_in[21]};

    char* wp = (char*)d_ws;
    auto alloc = [&](size_t bytes) {
        char* p = wp;
        wp += (bytes + 255) & ~(size_t)255;
        return p;
    };
    float* dinv  = (float*)alloc((size_t)N_NODES * 4);
    int*   cnt   = (int*)  alloc((size_t)N_NODES * 4);
    int*   ptr   = (int*)  alloc((size_t)(N_NODES + 1) * 4);
    int*   ptr2  = (int*)  alloc((size_t)N_NODES * 4);
    int*   esrc  = (int*)  alloc((size_t)N_EDGES * 4);
    u16*   bufA  = (u16*)  alloc((size_t)NPAD * HID * 2);
    u16*   bufB  = (u16*)  alloc((size_t)NPAD * HID * 2);
    float* zbuf  = (float*)alloc((size_t)N_NODES * 8 * 4);
    float* part0 = (float*)alloc((size_t)B0 * 12 * 4);
    float* partL = (float*)alloc((size_t)PB * 512 * 4);
    float* red   = (float*)alloc((size_t)PBR * 512 * 4);
    float* Wf1   = (float*)alloc((size_t)6 * HID * 4);
    u16*   WhiT  = (u16*)  alloc((size_t)HID * HID * 2);
    u16*   WloT  = (u16*)  alloc((size_t)HID * HID * 2);
    float* rv    = (float*)alloc(HID * 4);
    float* ps    = (float*)alloc(NG * HID * 4);
    int*   cg    = (int*)  alloc(NG * 4);
    (void)ws_size; (void)in_sizes; (void)n_in; (void)out_size;

    const int* rowi = ei;
    const int* coli = ei + N_EDGES;

    hipMemsetAsync(cnt, 0, (size_t)N_NODES * 4, stream);
    hipMemsetAsync(ps, 0, NG * HID * 4, stream);
    hipMemsetAsync(cg, 0, NG * 4, stream);

    // CSR + norms
    k_count<<<2048, 256, 0, stream>>>(coli, cnt);
    k_scan<<<1, 1024, 0, stream>>>(cnt, ptr, ptr2, dinv);
    for (int p = 0; p < 8; ++p)
        k_fillp<<<1024, 256, 0, stream>>>(rowi, coli, ptr2, esrc, p * FPART);
    k_batchcnt<<<(N_NODES + 255) / 256, 256, 0, stream>>>(batch, cg);

    // layer 1: aggregate in 6-dim raw space, then tiny GEMM with BN0 folded
    k_bn0stats<<<B0, 256, 0, stream>>>(pos, nrm, part0);
    k_fold6<<<1, 256, 0, stream>>>(W[0], part0, 1.0f / (float)N_NODES, bn0g, bn0b, Wf1, rv);
    k_agg6<<<N_NODES / 4, 256, 0, stream>>>(pos, nrm, ptr, esrc, dinv, zbuf);
    k_gemm1b<<<2048, 256, 0, stream>>>(zbuf, Wf1, rv, bb[0], bufA);   // bufA = a_1

    // layers 2..4: stats -> reduce -> fold BN_l into W_{l+1} -> MFMA gemm -> aggregate
    for (int l = 0; l < 3; ++l) {
        k_stats<<<PB, 256, 0, stream>>>(bufA, partL);
        k_reduce<<<PBR, 256, 0, stream>>>(partL, red);
        k_fold256<<<1, 256, 0, stream>>>(W[l + 1], red, 1.0f / (float)N_NODES,
                                         bg[l], bbt[l], WhiT, WloT, rv);
        k_gemm_mfma<<<NPAD / 64, 256, 0, stream>>>(bufA, WhiT, WloT, rv, bufB);
        k_agg<<<N_NODES / 4, 256, 0, stream>>>(bufB, ptr, esrc, dinv, bb[l + 1], bufA);
    }

    // final: fused stats+pool, then BN4 applied analytically on pooled sums
    k_statspool<<<PB, 256, 0, stream>>>(bufA, batch, partL, ps);
    k_reduce<<<PBR, 256, 0, stream>>>(partL, red);
    k_final<<<1, 256, 0, stream>>>(ps, cg, red, bg[3], bbt[3], (float*)d_out);
}

// Round 11
// 1692.457 us; speedup vs baseline: 2.7106x; 1.0173x over previous
//
#include <hip/hip_runtime.h>
#include <hip/hip_bf16.h>
#include <cstdint>

#define N_NODES 100000
#define NPAD    100032   // padded row count (multiple of 64)
#define N_EDGES 3200000
#define HID 256
#define NG 16
#define BN_EPS 1e-5f
#define B0 120       // bn0stats partial blocks
#define PB 1024      // stats partial blocks
#define SROWS ((N_NODES + PB - 1) / PB)   // 98 rows per stats block
#define PBR 128      // second-stage reduction blocks
#define RPR (PB / PBR)                    // 8 partial rows per reduce block
#define FPART 25000  // k_fill column-partition width (4 * 25000 = 100000)

typedef unsigned short u16;
using bf16x8 = __attribute__((ext_vector_type(8))) short;
using f32x4  = __attribute__((ext_vector_type(4))) float;

__device__ __forceinline__ float bf2f(u16 b) {
    return __uint_as_float(((unsigned)b) << 16);
}
__device__ __forceinline__ u16 f2bf(float f) {
    unsigned u = __float_as_uint(f);
    unsigned r = (u + 0x7FFFu + ((u >> 16) & 1u)) >> 16;
    return (u16)r;
}
__device__ __forceinline__ float4 ld_bf16x4(const u16* p) {
    ushort4 u = *reinterpret_cast<const ushort4*>(p);
    float4 f;
    f.x = bf2f(u.x); f.y = bf2f(u.y); f.z = bf2f(u.z); f.w = bf2f(u.w);
    return f;
}

// ---------------- CSR build ----------------
__global__ void k_count(const int* __restrict__ coli, int* __restrict__ cnt) {
    int i = blockIdx.x * blockDim.x + threadIdx.x;
    int st = gridDim.x * blockDim.x;
    for (; i < N_EDGES; i += st) atomicAdd(&cnt[coli[i]], 1);
}

// 1024-thread single-block scan (wave-shuffle) + fused dinv; writes ptr AND ptr2
__global__ void k_scan(const int* __restrict__ cnt, int* __restrict__ ptr,
                       int* __restrict__ ptr2, float* __restrict__ dinv) {
    __shared__ int wsum[16];
    const int t = threadIdx.x;
    const int wv = t >> 6;
    const int ln = t & 63;
    int carry = 0;
    for (int base = 0; base < N_NODES; base += 4096) {
        int idx = base + t * 4;
        int v0 = 0, v1 = 0, v2 = 0, v3 = 0;
        if (idx + 3 < N_NODES) {
            int4 q = *reinterpret_cast<const int4*>(&cnt[idx]);
            v0 = q.x; v1 = q.y; v2 = q.z; v3 = q.w;
        } else {
            if (idx + 0 < N_NODES) v0 = cnt[idx + 0];
            if (idx + 1 < N_NODES) v1 = cnt[idx + 1];
            if (idx + 2 < N_NODES) v2 = cnt[idx + 2];
        }
        if (idx + 0 < N_NODES) dinv[idx + 0] = rsqrtf((float)v0 + 1.0f);
        if (idx + 1 < N_NODES) dinv[idx + 1] = rsqrtf((float)v1 + 1.0f);
        if (idx + 2 < N_NODES) dinv[idx + 2] = rsqrtf((float)v2 + 1.0f);
        if (idx + 3 < N_NODES) dinv[idx + 3] = rsqrtf((float)v3 + 1.0f);
        int s = v0 + v1 + v2 + v3;
        int sc = s;
        for (int off = 1; off < 64; off <<= 1) {
            int u = __shfl_up(sc, off);
            if (ln >= off) sc += u;
        }
        if (ln == 63) wsum[wv] = sc;
        __syncthreads();
        if (wv == 0 && ln < 16) {
            int a = wsum[ln];
            for (int off = 1; off < 16; off <<= 1) {
                int u = __shfl_up(a, off, 16);
                if (ln >= off) a += u;
            }
            wsum[ln] = a;
        }
        __syncthreads();
        int total = wsum[15];
        int excl = carry + (wv ? wsum[wv - 1] : 0) + sc - s;
        if (idx + 0 < N_NODES) { ptr[idx + 0] = excl; ptr2[idx + 0] = excl; } excl += v0;
        if (idx + 1 < N_NODES) { ptr[idx + 1] = excl; ptr2[idx + 1] = excl; } excl += v1;
        if (idx + 2 < N_NODES) { ptr[idx + 2] = excl; ptr2[idx + 2] = excl; } excl += v2;
        if (idx + 3 < N_NODES) { ptr[idx + 3] = excl; ptr2[idx + 3] = excl; }
        __syncthreads();
        carry += total;
    }
    if (t == 0) ptr[N_NODES] = carry;
}

// partitioned fill: this pass only handles cols in [lo, lo+FPART).
__global__ void k_fillp(const int* __restrict__ rowi, const int* __restrict__ coli,
                        int* __restrict__ ptr2, int* __restrict__ esrc, int lo) {
    int i = blockIdx.x * blockDim.x + threadIdx.x;
    int st = gridDim.x * blockDim.x;
    const int hi = lo + FPART;
    for (; i < N_EDGES; i += st) {
        int c = coli[i];
        if (c >= lo && c < hi) {
            int p = atomicAdd(&ptr2[c], 1);
            esrc[p] = rowi[i];
        }
    }
}

// per-block LDS histogram -> 16 global atomics per block
__global__ __launch_bounds__(256) void k_batchcnt(const int* __restrict__ batch,
                                                  int* __restrict__ cg) {
    __shared__ int h[NG];
    if (threadIdx.x < NG) h[threadIdx.x] = 0;
    __syncthreads();
    int i = blockIdx.x * blockDim.x + threadIdx.x;
    if (i < N_NODES) atomicAdd(&h[batch[i]], 1);
    __syncthreads();
    if (threadIdx.x < NG) {
        int v = h[threadIdx.x];
        if (v) atomicAdd(&cg[threadIdx.x], v);
    }
}

// ---------------- BN0 stats: block-reduced partials ----------------
__global__ __launch_bounds__(256) void k_bn0stats(const float* __restrict__ pos,
                                                  const float* __restrict__ nrm,
                                                  float* __restrict__ part /* B0*12 */) {
    float s[6] = {0, 0, 0, 0, 0, 0}, q[6] = {0, 0, 0, 0, 0, 0};
    int i = blockIdx.x * blockDim.x + threadIdx.x;
    int stp = gridDim.x * blockDim.x;
    for (; i < N_NODES; i += stp) {
        float v;
        v = pos[i * 3 + 0]; s[0] += v; q[0] += v * v;
        v = pos[i * 3 + 1]; s[1] += v; q[1] += v * v;
        v = pos[i * 3 + 2]; s[2] += v; q[2] += v * v;
        v = nrm[i * 3 + 0]; s[3] += v; q[3] += v * v;
        v = nrm[i * 3 + 1]; s[4] += v; q[4] += v * v;
        v = nrm[i * 3 + 2]; s[5] += v; q[5] += v * v;
    }
#pragma unroll
    for (int k = 0; k < 6; ++k) {
        for (int o = 32; o > 0; o >>= 1) { s[k] += __shfl_down(s[k], o); q[k] += __shfl_down(q[k], o); }
    }
    __shared__ float ls[4][12];
    const int wv = threadIdx.x >> 6;
    const int ln = threadIdx.x & 63;
    if (ln == 0) {
#pragma unroll
        for (int k = 0; k < 6; ++k) { ls[wv][k] = s[k]; ls[wv][6 + k] = q[k]; }
    }
    __syncthreads();
    if (threadIdx.x < 12)
        part[blockIdx.x * 12 + threadIdx.x] =
            ls[0][threadIdx.x] + ls[1][threadIdx.x] + ls[2][threadIdx.x] + ls[3][threadIdx.x];
}

// ---------------- fold BN0 into W1 (K=6): Wf=A*W, rvB = B^T W ----------------
__global__ void k_fold6(const float* __restrict__ W,
                        const float* __restrict__ part, float invcnt,
                        const float* __restrict__ gamma, const float* __restrict__ beta,
                        float* __restrict__ Wf, float* __restrict__ rvB) {
    __shared__ float st[12];
    int c = threadIdx.x;
    if (c < 12) {
        float a = 0.f;
        for (int b = 0; b < B0; ++b) a += part[b * 12 + c];
        st[c] = a;
    }
    __syncthreads();
    float acc = 0.f;
    for (int k = 0; k < 6; ++k) {
        float m = st[k] * invcnt;
        float var = st[6 + k] * invcnt - m * m;
        float A = gamma[k] * rsqrtf(var + BN_EPS);
        float B = beta[k] - m * A;
        float w = W[k * HID + c];
        Wf[k * HID + c] = A * w;
        acc = fmaf(B, w, acc);
    }
    rvB[c] = acc;
}

// ---------------- second-stage reduction of stats partials: PB -> PBR rows ------
__global__ __launch_bounds__(256) void k_reduce(const float* __restrict__ part,
                                                float* __restrict__ red) {
    const int b = blockIdx.x;
    const int t = threadIdx.x;
    float a0 = 0.f, a1 = 0.f;
#pragma unroll
    for (int r = 0; r < RPR; ++r) {
        const float* p = &part[(size_t)(b * RPR + r) * 512];
        a0 += p[t];
        a1 += p[t + 256];
    }
    red[(size_t)b * 512 + t] = a0;
    red[(size_t)b * 512 + 256 + t] = a1;
}

// ---------------- fold for K=256 (reduces PBR reduced partials in preamble) -----
__global__ void k_fold256(const float* __restrict__ W,
                          const float* __restrict__ red /* PBR*512 */, float invcnt,
                          const float* __restrict__ gamma, const float* __restrict__ beta,
                          u16* __restrict__ WhiT, u16* __restrict__ WloT,
                          float* __restrict__ rv) {
    __shared__ float ss[HID], sq[HID];
    int c = threadIdx.x;
    {
        float a = 0.f, b = 0.f;
#pragma unroll 4
        for (int bb = 0; bb < PBR; ++bb) {
            a += red[bb * 512 + c];
            b += red[bb * 512 + HID + c];
        }
        ss[c] = a; sq[c] = b;
    }
    __syncthreads();
    float acc = 0.f;
    for (int k = 0; k < HID; ++k) {
        float m = ss[k] * invcnt;
        float var = sq[k] * invcnt - m * m;
        float A = gamma[k] * rsqrtf(var + BN_EPS);
        float B = beta[k] - m * A;
        float w = W[k * HID + c];
        float wf = A * w;
        u16 hi = f2bf(wf);
        WhiT[c * HID + k] = hi;
        WloT[c * HID + k] = f2bf(wf - bf2f(hi));
        acc = fmaf(B, w, acc);
    }
    rv[c] = acc;
}

// ---------------- layer-1 pre-aggregation in 6-dim raw space ----------------
__global__ __launch_bounds__(256) void k_agg6(
    const float* __restrict__ pos, const float* __restrict__ nrm,
    const int* __restrict__ ptr, const int* __restrict__ esrc,
    const float* __restrict__ dinv, float* __restrict__ z) {
    const int wv = threadIdx.x >> 6;
    const int ln = threadIdx.x & 63;
    const int n = blockIdx.x * 4 + wv;
    const float dn = dinv[n];
    float z0 = 0, z1 = 0, z2 = 0, z3 = 0, z4 = 0, z5 = 0, t = 0;
    const int s_ = ptr[n], e_ = ptr[n + 1];
    for (int e = s_ + ln; e < e_; e += 64) {
        int src = esrc[e];
        float w = dn * dinv[src];
        z0 = fmaf(w, pos[src * 3 + 0], z0);
        z1 = fmaf(w, pos[src * 3 + 1], z1);
        z2 = fmaf(w, pos[src * 3 + 2], z2);
        z3 = fmaf(w, nrm[src * 3 + 0], z3);
        z4 = fmaf(w, nrm[src * 3 + 1], z4);
        z5 = fmaf(w, nrm[src * 3 + 2], z5);
        t += w;
    }
    if (ln == 0) {   // self loop
        float sl = dn * dn;
        z0 = fmaf(sl, pos[n * 3 + 0], z0);
        z1 = fmaf(sl, pos[n * 3 + 1], z1);
        z2 = fmaf(sl, pos[n * 3 + 2], z2);
        z3 = fmaf(sl, nrm[n * 3 + 0], z3);
        z4 = fmaf(sl, nrm[n * 3 + 1], z4);
        z5 = fmaf(sl, nrm[n * 3 + 2], z5);
        t += sl;
    }
#pragma unroll
    for (int o = 1; o < 64; o <<= 1) {
        z0 += __shfl_xor(z0, o); z1 += __shfl_xor(z1, o); z2 += __shfl_xor(z2, o);
        z3 += __shfl_xor(z3, o); z4 += __shfl_xor(z4, o); z5 += __shfl_xor(z5, o);
        t  += __shfl_xor(t, o);
    }
    if (ln == 0) {
        *reinterpret_cast<f32x4*>(&z[n * 8])     = f32x4{z0, z1, z2, z3};
        *reinterpret_cast<f32x4*>(&z[n * 8 + 4]) = f32x4{z4, z5, t, 0.f};
    }
}

// ---------------- layer-1: y1 = relu(z6 @ Wf + s*rvB + b1) -> bf16 ----------------
__global__ __launch_bounds__(256) void k_gemm1b(
    const float* __restrict__ z, const float* __restrict__ Wf,
    const float* __restrict__ rvB, const float* __restrict__ b1,
    u16* __restrict__ out) {
    const int c = threadIdx.x;
    float w0 = Wf[0 * HID + c], w1 = Wf[1 * HID + c], w2 = Wf[2 * HID + c];
    float w3 = Wf[3 * HID + c], w4 = Wf[4 * HID + c], w5 = Wf[5 * HID + c];
    const float rvc = rvB[c], bc = b1[c];
    for (int n = blockIdx.x; n < N_NODES; n += gridDim.x) {
        float x0 = z[n * 8 + 0], x1 = z[n * 8 + 1], x2 = z[n * 8 + 2];
        float x3 = z[n * 8 + 3], x4 = z[n * 8 + 4], x5 = z[n * 8 + 5];
        float s  = z[n * 8 + 6];
        float acc = fmaf(s, rvc, bc);
        acc = fmaf(x0, w0, acc); acc = fmaf(x1, w1, acc); acc = fmaf(x2, w2, acc);
        acc = fmaf(x3, w3, acc); acc = fmaf(x4, w4, acc); acc = fmaf(x5, w5, acc);
        out[(size_t)n * HID + c] = f2bf(fmaxf(acc, 0.f));
    }
}

// ---------------- MFMA GEMM on padded [NPAD,256]: no bounds checks ----------------
__global__ __launch_bounds__(256) void k_gemm_mfma(
    const u16* __restrict__ X, const u16* __restrict__ WhiT,
    const u16* __restrict__ WloT, const float* __restrict__ rv,
    u16* __restrict__ out) {
    const int tid = threadIdx.x;
    const int wv = tid >> 6;
    const int ln = tid & 63;
    const int row0 = blockIdx.x * 64;
    const int lr = ln & 15;
    const int lk = (ln >> 4) * 8;
    const int wcol0 = wv * 64;

    f32x4 acc[4][4] = {};
    for (int kk = 0; kk < HID; kk += 32) {
        bf16x8 a[4], bh[4], bl[4];
#pragma unroll
        for (int i = 0; i < 4; ++i) {
            int r = row0 + i * 16 + lr;
            a[i] = *reinterpret_cast<const bf16x8*>(&X[(size_t)r * HID + kk + lk]);
        }
#pragma unroll
        for (int c = 0; c < 4; ++c) {
            int col = wcol0 + c * 16 + lr;
            bh[c] = *reinterpret_cast<const bf16x8*>(&WhiT[(size_t)col * HID + kk + lk]);
            bl[c] = *reinterpret_cast<const bf16x8*>(&WloT[(size_t)col * HID + kk + lk]);
        }
#pragma unroll
        for (int i = 0; i < 4; ++i)
#pragma unroll
            for (int c = 0; c < 4; ++c) {
                acc[i][c] = __builtin_amdgcn_mfma_f32_16x16x32_bf16(a[i], bh[c], acc[i][c], 0, 0, 0);
                acc[i][c] = __builtin_amdgcn_mfma_f32_16x16x32_bf16(a[i], bl[c], acc[i][c], 0, 0, 0);
            }
    }
    const int crow = (ln >> 4) * 4;
#pragma unroll
    for (int c = 0; c < 4; ++c) {
        int col = wcol0 + c * 16 + lr;
        float rvc = rv[col];
#pragma unroll
        for (int i = 0; i < 4; ++i) {
#pragma unroll
            for (int rg = 0; rg < 4; ++rg) {
                int r = row0 + i * 16 + crow + rg;
                out[(size_t)r * HID + col] = f2bf(acc[i][c][rg] + rvc);
            }
        }
    }
}

// -------- aggregation: y = relu(S.xw + bias); 64-edge index prefetch + MLP-4 ----
__global__ __launch_bounds__(256) void k_agg(
    const u16* __restrict__ xw, const int* __restrict__ ptr,
    const int* __restrict__ esrc, const float* __restrict__ dinv,
    const float* __restrict__ bias, u16* __restrict__ y) {
    const int wv = threadIdx.x >> 6;
    const int ln = threadIdx.x & 63;
    const int n = blockIdx.x * 4 + wv;
    const float dn = dinv[n];
    const size_t base = (size_t)n * HID + ln * 4;
    float4 v = ld_bf16x4(&xw[base]);
    const float sl = dn * dn;
    float a0 = v.x * sl, a1 = v.y * sl, a2 = v.z * sl, a3 = v.w * sl;
    const int s = ptr[n], e = ptr[n + 1];
    for (int bs = s; bs < e; bs += 64) {
        const int cnt = (e - bs < 64) ? e - bs : 64;
        int myidx = 0;
        float myw = 0.f;
        if (ln < cnt) {
            myidx = esrc[bs + ln];
            myw = dinv[myidx] * dn;
        }
        int j = 0;
        for (; j + 3 < cnt; j += 4) {
            int   s0 = __shfl(myidx, j),     s1 = __shfl(myidx, j + 1);
            int   s2 = __shfl(myidx, j + 2), s3 = __shfl(myidx, j + 3);
            float w0 = __shfl(myw, j),       w1 = __shfl(myw, j + 1);
            float w2 = __shfl(myw, j + 2),   w3 = __shfl(myw, j + 3);
            float4 u0 = ld_bf16x4(&xw[(size_t)s0 * HID + ln * 4]);
            float4 u1 = ld_bf16x4(&xw[(size_t)s1 * HID + ln * 4]);
            float4 u2 = ld_bf16x4(&xw[(size_t)s2 * HID + ln * 4]);
            float4 u3 = ld_bf16x4(&xw[(size_t)s3 * HID + ln * 4]);
            a0 = fmaf(w0, u0.x, a0); a1 = fmaf(w0, u0.y, a1);
            a2 = fmaf(w0, u0.z, a2); a3 = fmaf(w0, u0.w, a3);
            a0 = fmaf(w1, u1.x, a0); a1 = fmaf(w1, u1.y, a1);
            a2 = fmaf(w1, u1.z, a2); a3 = fmaf(w1, u1.w, a3);
            a0 = fmaf(w2, u2.x, a0); a1 = fmaf(w2, u2.y, a1);
            a2 = fmaf(w2, u2.z, a2); a3 = fmaf(w2, u2.w, a3);
            a0 = fmaf(w3, u3.x, a0); a1 = fmaf(w3, u3.y, a1);
            a2 = fmaf(w3, u3.z, a2); a3 = fmaf(w3, u3.w, a3);
        }
        for (; j < cnt; ++j) {
            int   s0 = __shfl(myidx, j);
            float w0 = __shfl(myw, j);
            float4 u0 = ld_bf16x4(&xw[(size_t)s0 * HID + ln * 4]);
            a0 = fmaf(w0, u0.x, a0); a1 = fmaf(w0, u0.y, a1);
            a2 = fmaf(w0, u0.z, a2); a3 = fmaf(w0, u0.w, a3);
        }
    }
    float4 b = *reinterpret_cast<const float4*>(&bias[ln * 4]);
    a0 = fmaxf(a0 + b.x, 0.f);
    a1 = fmaxf(a1 + b.y, 0.f);
    a2 = fmaxf(a2 + b.z, 0.f);
    a3 = fmaxf(a3 + b.w, 0.f);
    ushort4 o;
    o.x = f2bf(a0); o.y = f2bf(a1); o.z = f2bf(a2); o.w = f2bf(a3);
    *reinterpret_cast<ushort4*>(&y[base]) = o;
}

// ------- per-channel stats partials: vectorized (4 row-lanes x 64 ch-quads) ------
__global__ __launch_bounds__(256) void k_stats(const u16* __restrict__ y,
                                               float* __restrict__ part /* PB*512 */) {
    const int t = threadIdx.x;
    const int cl = t & 63;          // channel quad: channels cl*4 .. cl*4+3
    const int rp = t >> 6;          // row parity 0..3
    const int n0 = blockIdx.x * SROWS;
    const int n1 = (n0 + SROWS < N_NODES) ? n0 + SROWS : N_NODES;
    float s0 = 0, s1 = 0, s2 = 0, s3 = 0, q0 = 0, q1 = 0, q2 = 0, q3 = 0;
    for (int n = n0 + rp; n < n1; n += 4) {
        float4 v = ld_bf16x4(&y[(size_t)n * HID + cl * 4]);
        s0 += v.x; q0 = fmaf(v.x, v.x, q0);
        s1 += v.y; q1 = fmaf(v.y, v.y, q1);
        s2 += v.z; q2 = fmaf(v.z, v.z, q2);
        s3 += v.w; q3 = fmaf(v.w, v.w, q3);
    }
    __shared__ float sh[4 * 512];
    float* shr = &sh[rp * 512];
    shr[cl * 4 + 0] = s0; shr[cl * 4 + 1] = s1;
    shr[cl * 4 + 2] = s2; shr[cl * 4 + 3] = s3;
    shr[256 + cl * 4 + 0] = q0; shr[256 + cl * 4 + 1] = q1;
    shr[256 + cl * 4 + 2] = q2; shr[256 + cl * 4 + 3] = q3;
    __syncthreads();
    float a = sh[t] + sh[512 + t] + sh[1024 + t] + sh[1536 + t];
    float b = sh[256 + t] + sh[768 + t] + sh[1280 + t] + sh[1792 + t];
    part[blockIdx.x * 512 + t] = a;
    part[blockIdx.x * 512 + 256 + t] = b;
}

// ---------------- stats + pooled sums fused (batch sorted) ----------------
__global__ __launch_bounds__(256) void k_statspool(const u16* __restrict__ y,
                                                   const int* __restrict__ batch,
                                                   float* __restrict__ part,
                                                   float* __restrict__ ps) {
    const int c = threadIdx.x;
    const int n0 = blockIdx.x * SROWS;
    const int n1 = (n0 + SROWS < N_NODES) ? n0 + SROWS : N_NODES;
    float s = 0.f, q = 0.f;
    if (n0 < N_NODES) {
        int cur = batch[n0];
        float acc = 0.f;
        for (int n = n0; n < n1; ++n) {
            float v = bf2f(y[(size_t)n * HID + c]);
            int g = batch[n];
            if (g != cur) {
                atomicAdd(&ps[cur * HID + c], acc);
                acc = 0.f;
                cur = g;
            }
            s += v;
            q = fmaf(v, v, q);
            acc += v;
        }
        atomicAdd(&ps[cur * HID + c], acc);
    }
    part[blockIdx.x * 512 + c] = s;
    part[blockIdx.x * 512 + HID + c] = q;
}

// ---------------- finalize: BN4 affine on pooled sums (reduces PBR partials) ----
__global__ void k_final(const float* __restrict__ ps, const int* __restrict__ cg,
                        const float* __restrict__ red, const float* __restrict__ gamma,
                        const float* __restrict__ beta, float* __restrict__ out) {
    __shared__ float ss[HID], sq[HID];
    const int c = threadIdx.x;
    {
        float a = 0.f, b = 0.f;
#pragma unroll 4
        for (int bb = 0; bb < PBR; ++bb) {
            a += red[bb * 512 + c];
            b += red[bb * 512 + HID + c];
        }
        ss[c] = a; sq[c] = b;
    }
    __syncthreads();
    const float invn = 1.0f / (float)N_NODES;
    float m = ss[c] * invn;
    float var = sq[c] * invn - m * m;
    float A = gamma[c] * rsqrtf(var + BN_EPS);
    float B = beta[c] - m * A;
    for (int g = 0; g < NG; ++g) {
        float cn = (float)cg[g];
        float val = (A * ps[g * HID + c] + cn * B) / fmaxf(cn, 1.0f);
        out[g * HID + c] = val;
    }
}

extern "C" void kernel_launch(void* const* d_in, const int* in_sizes, int n_in,
                              void* d_out, int out_size, void* d_ws, size_t ws_size,
                              hipStream_t stream) {
    const float* pos   = (const float*)d_in[0];
    const float* nrm   = (const float*)d_in[1];
    const int*   ei    = (const int*)d_in[2];
    const int*   batch = (const int*)d_in[3];
    const float* bn0g  = (const float*)d_in[4];
    const float* bn0b  = (const float*)d_in[5];
    const float* W[4]   = {(const float*)d_in[6],  (const float*)d_in[10], (const float*)d_in[14], (const float*)d_in[18]};
    const float* bb[4]  = {(const float*)d_in[7],  (const float*)d_in[11], (const float*)d_in[15], (const float*)d_in[19]};
    const float* bg[4]  = {(const float*)d_in[8],  (const float*)d_in[12], (const float*)d_in[16], (const float*)d_in[20]};
    const float* bbt[4] = {(const float*)d_in[9],  (const float*)d_in[13], (const float*)d_in[17], (const float*)d_in[21]};

    char* wp = (char*)d_ws;
    auto alloc = [&](size_t bytes) {
        char* p = wp;
        wp += (bytes + 255) & ~(size_t)255;
        return p;
    };
    float* dinv  = (float*)alloc((size_t)N_NODES * 4);
    int*   cnt   = (int*)  alloc((size_t)N_NODES * 4);
    int*   ptr   = (int*)  alloc((size_t)(N_NODES + 1) * 4);
    int*   ptr2  = (int*)  alloc((size_t)N_NODES * 4);
    int*   esrc  = (int*)  alloc((size_t)N_EDGES * 4);
    u16*   bufA  = (u16*)  alloc((size_t)NPAD * HID * 2);
    u16*   bufB  = (u16*)  alloc((size_t)NPAD * HID * 2);
    float* zbuf  = (float*)alloc((size_t)N_NODES * 8 * 4);
    float* part0 = (float*)alloc((size_t)B0 * 12 * 4);
    float* partL = (float*)alloc((size_t)PB * 512 * 4);
    float* red   = (float*)alloc((size_t)PBR * 512 * 4);
    float* Wf1   = (float*)alloc((size_t)6 * HID * 4);
    u16*   WhiT  = (u16*)  alloc((size_t)HID * HID * 2);
    u16*   WloT  = (u16*)  alloc((size_t)HID * HID * 2);
    float* rv    = (float*)alloc(HID * 4);
    float* ps    = (float*)alloc(NG * HID * 4);
    int*   cg    = (int*)  alloc(NG * 4);
    (void)ws_size; (void)in_sizes; (void)n_in; (void)out_size;

    const int* rowi = ei;
    const int* coli = ei + N_EDGES;

    hipMemsetAsync(cnt, 0, (size_t)N_NODES * 4, stream);
    hipMemsetAsync(ps, 0, NG * HID * 4, stream);
    hipMemsetAsync(cg, 0, NG * 4, stream);

    // CSR + norms
    k_count<<<2048, 256, 0, stream>>>(coli, cnt);
    k_scan<<<1, 1024, 0, stream>>>(cnt, ptr, ptr2, dinv);
    for (int p = 0; p < 4; ++p)
        k_fillp<<<1024, 256, 0, stream>>>(rowi, coli, ptr2, esrc, p * FPART);
    k_batchcnt<<<(N_NODES + 255) / 256, 256, 0, stream>>>(batch, cg);

    // layer 1: aggregate in 6-dim raw space, then tiny GEMM with BN0 folded
    k_bn0stats<<<B0, 256, 0, stream>>>(pos, nrm, part0);
    k_fold6<<<1, 256, 0, stream>>>(W[0], part0, 1.0f / (float)N_NODES, bn0g, bn0b, Wf1, rv);
    k_agg6<<<N_NODES / 4, 256, 0, stream>>>(pos, nrm, ptr, esrc, dinv, zbuf);
    k_gemm1b<<<2048, 256, 0, stream>>>(zbuf, Wf1, rv, bb[0], bufA);   // bufA = a_1

    // layers 2..4: stats -> reduce -> fold BN_l into W_{l+1} -> MFMA gemm -> aggregate
    for (int l = 0; l < 3; ++l) {
        k_stats<<<PB, 256, 0, stream>>>(bufA, partL);
        k_reduce<<<PBR, 256, 0, stream>>>(partL, red);
        k_fold256<<<1, 256, 0, stream>>>(W[l + 1], red, 1.0f / (float)N_NODES,
                                         bg[l], bbt[l], WhiT, WloT, rv);
        k_gemm_mfma<<<NPAD / 64, 256, 0, stream>>>(bufA, WhiT, WloT, rv, bufB);
        k_agg<<<N_NODES / 4, 256, 0, stream>>>(bufB, ptr, esrc, dinv, bb[l + 1], bufA);
    }

    // final: fused stats+pool, then BN4 applied analytically on pooled sums
    k_statspool<<<PB, 256, 0, stream>>>(bufA, batch, partL, ps);
    k_reduce<<<PBR, 256, 0, stream>>>(partL, red);
    k_final<<<1, 256, 0, stream>>>(ps, cg, red, bg[3], bbt[3], (float*)d_out);
}

// Round 12
// 1614.665 us; speedup vs baseline: 2.8412x; 1.0482x over previous
//
#include <hip/hip_runtime.h>
#include <hip/hip_bf16.h>
#include <cstdint>

#define N_NODES 100000
#define NPAD    100032   // padded row count (multiple of 64)
#define N_EDGES 3200000
#define HID 256
#define NG 16
#define BN_EPS 1e-5f
#define B0 120       // bn0stats partial blocks
#define PB 1024      // stats partial blocks
#define SROWS ((N_NODES + PB - 1) / PB)   // 98 rows per stats block
#define PBR 128      // second-stage reduction blocks
#define RPR (PB / PBR)                    // 8 partial rows per reduce block
#define FPART 25000  // k_fill column-partition width (4 * 25000 = 100000)
#define LDSROW 264   // padded LDS row stride in elements (264*2=528B == 4-bank step)

typedef unsigned short u16;
using bf16x8 = __attribute__((ext_vector_type(8))) short;
using f32x4  = __attribute__((ext_vector_type(4))) float;

__device__ __forceinline__ float bf2f(u16 b) {
    return __uint_as_float(((unsigned)b) << 16);
}
__device__ __forceinline__ u16 f2bf(float f) {
    unsigned u = __float_as_uint(f);
    unsigned r = (u + 0x7FFFu + ((u >> 16) & 1u)) >> 16;
    return (u16)r;
}
__device__ __forceinline__ float4 ld_bf16x4(const u16* p) {
    ushort4 u = *reinterpret_cast<const ushort4*>(p);
    float4 f;
    f.x = bf2f(u.x); f.y = bf2f(u.y); f.z = bf2f(u.z); f.w = bf2f(u.w);
    return f;
}

// ---------------- CSR build ----------------
__global__ void k_count(const int* __restrict__ coli, int* __restrict__ cnt) {
    int i = blockIdx.x * blockDim.x + threadIdx.x;
    int st = gridDim.x * blockDim.x;
    for (; i < N_EDGES; i += st) atomicAdd(&cnt[coli[i]], 1);
}

// 1024-thread single-block scan (wave-shuffle) + fused dinv; writes ptr AND ptr2
__global__ void k_scan(const int* __restrict__ cnt, int* __restrict__ ptr,
                       int* __restrict__ ptr2, float* __restrict__ dinv) {
    __shared__ int wsum[16];
    const int t = threadIdx.x;
    const int wv = t >> 6;
    const int ln = t & 63;
    int carry = 0;
    for (int base = 0; base < N_NODES; base += 4096) {
        int idx = base + t * 4;
        int v0 = 0, v1 = 0, v2 = 0, v3 = 0;
        if (idx + 3 < N_NODES) {
            int4 q = *reinterpret_cast<const int4*>(&cnt[idx]);
            v0 = q.x; v1 = q.y; v2 = q.z; v3 = q.w;
        } else {
            if (idx + 0 < N_NODES) v0 = cnt[idx + 0];
            if (idx + 1 < N_NODES) v1 = cnt[idx + 1];
            if (idx + 2 < N_NODES) v2 = cnt[idx + 2];
        }
        if (idx + 0 < N_NODES) dinv[idx + 0] = rsqrtf((float)v0 + 1.0f);
        if (idx + 1 < N_NODES) dinv[idx + 1] = rsqrtf((float)v1 + 1.0f);
        if (idx + 2 < N_NODES) dinv[idx + 2] = rsqrtf((float)v2 + 1.0f);
        if (idx + 3 < N_NODES) dinv[idx + 3] = rsqrtf((float)v3 + 1.0f);
        int s = v0 + v1 + v2 + v3;
        int sc = s;
        for (int off = 1; off < 64; off <<= 1) {
            int u = __shfl_up(sc, off);
            if (ln >= off) sc += u;
        }
        if (ln == 63) wsum[wv] = sc;
        __syncthreads();
        if (wv == 0 && ln < 16) {
            int a = wsum[ln];
            for (int off = 1; off < 16; off <<= 1) {
                int u = __shfl_up(a, off, 16);
                if (ln >= off) a += u;
            }
            wsum[ln] = a;
        }
        __syncthreads();
        int total = wsum[15];
        int excl = carry + (wv ? wsum[wv - 1] : 0) + sc - s;
        if (idx + 0 < N_NODES) { ptr[idx + 0] = excl; ptr2[idx + 0] = excl; } excl += v0;
        if (idx + 1 < N_NODES) { ptr[idx + 1] = excl; ptr2[idx + 1] = excl; } excl += v1;
        if (idx + 2 < N_NODES) { ptr[idx + 2] = excl; ptr2[idx + 2] = excl; } excl += v2;
        if (idx + 3 < N_NODES) { ptr[idx + 3] = excl; ptr2[idx + 3] = excl; }
        __syncthreads();
        carry += total;
    }
    if (t == 0) ptr[N_NODES] = carry;
}

// partitioned fill: this pass only handles cols in [lo, lo+FPART).
__global__ void k_fillp(const int* __restrict__ rowi, const int* __restrict__ coli,
                        int* __restrict__ ptr2, int* __restrict__ esrc, int lo) {
    int i = blockIdx.x * blockDim.x + threadIdx.x;
    int st = gridDim.x * blockDim.x;
    const int hi = lo + FPART;
    for (; i < N_EDGES; i += st) {
        int c = coli[i];
        if (c >= lo && c < hi) {
            int r = rowi[i];
            int p = atomicAdd(&ptr2[c], 1);
            esrc[p] = r;
        }
    }
}

// ---------------- BN0 stats + batch histogram fused ----------------
__global__ __launch_bounds__(256) void k_bn0stats(const float* __restrict__ pos,
                                                  const float* __restrict__ nrm,
                                                  const int* __restrict__ batch,
                                                  float* __restrict__ part /* B0*12 */,
                                                  int* __restrict__ cg) {
    __shared__ int h[NG];
    if (threadIdx.x < NG) h[threadIdx.x] = 0;
    __syncthreads();
    float s[6] = {0, 0, 0, 0, 0, 0}, q[6] = {0, 0, 0, 0, 0, 0};
    int i = blockIdx.x * blockDim.x + threadIdx.x;
    int stp = gridDim.x * blockDim.x;
    for (; i < N_NODES; i += stp) {
        float v;
        v = pos[i * 3 + 0]; s[0] += v; q[0] += v * v;
        v = pos[i * 3 + 1]; s[1] += v; q[1] += v * v;
        v = pos[i * 3 + 2]; s[2] += v; q[2] += v * v;
        v = nrm[i * 3 + 0]; s[3] += v; q[3] += v * v;
        v = nrm[i * 3 + 1]; s[4] += v; q[4] += v * v;
        v = nrm[i * 3 + 2]; s[5] += v; q[5] += v * v;
        atomicAdd(&h[batch[i]], 1);
    }
#pragma unroll
    for (int k = 0; k < 6; ++k) {
        for (int o = 32; o > 0; o >>= 1) { s[k] += __shfl_down(s[k], o); q[k] += __shfl_down(q[k], o); }
    }
    __shared__ float ls[4][12];
    const int wv = threadIdx.x >> 6;
    const int ln = threadIdx.x & 63;
    if (ln == 0) {
#pragma unroll
        for (int k = 0; k < 6; ++k) { ls[wv][k] = s[k]; ls[wv][6 + k] = q[k]; }
    }
    __syncthreads();
    if (threadIdx.x < 12)
        part[blockIdx.x * 12 + threadIdx.x] =
            ls[0][threadIdx.x] + ls[1][threadIdx.x] + ls[2][threadIdx.x] + ls[3][threadIdx.x];
    if (threadIdx.x < NG) {
        int v = h[threadIdx.x];
        if (v) atomicAdd(&cg[threadIdx.x], v);
    }
}

// ---------------- fold BN0 into W1 (K=6): Wf=A*W, rvB = B^T W ----------------
__global__ void k_fold6(const float* __restrict__ W,
                        const float* __restrict__ part, float invcnt,
                        const float* __restrict__ gamma, const float* __restrict__ beta,
                        float* __restrict__ Wf, float* __restrict__ rvB) {
    __shared__ float st[12];
    int c = threadIdx.x;
    if (c < 12) {
        float a = 0.f;
        for (int b = 0; b < B0; ++b) a += part[b * 12 + c];
        st[c] = a;
    }
    __syncthreads();
    float acc = 0.f;
    for (int k = 0; k < 6; ++k) {
        float m = st[k] * invcnt;
        float var = st[6 + k] * invcnt - m * m;
        float A = gamma[k] * rsqrtf(var + BN_EPS);
        float B = beta[k] - m * A;
        float w = W[k * HID + c];
        Wf[k * HID + c] = A * w;
        acc = fmaf(B, w, acc);
    }
    rvB[c] = acc;
}

// ---------------- second-stage reduction of stats partials: PB -> PBR rows ------
__global__ __launch_bounds__(256) void k_reduce(const float* __restrict__ part,
                                                float* __restrict__ red) {
    const int b = blockIdx.x;
    const int t = threadIdx.x;
    float a0 = 0.f, a1 = 0.f;
#pragma unroll
    for (int r = 0; r < RPR; ++r) {
        const float* p = &part[(size_t)(b * RPR + r) * 512];
        a0 += p[t];
        a1 += p[t + 256];
    }
    red[(size_t)b * 512 + t] = a0;
    red[(size_t)b * 512 + 256 + t] = a1;
}

// ---------------- fold for K=256 (reduces PBR reduced partials in preamble) -----
__global__ void k_fold256(const float* __restrict__ W,
                          const float* __restrict__ red /* PBR*512 */, float invcnt,
                          const float* __restrict__ gamma, const float* __restrict__ beta,
                          u16* __restrict__ WhiT, u16* __restrict__ WloT,
                          float* __restrict__ rv) {
    __shared__ float ss[HID], sq[HID];
    int c = threadIdx.x;
    {
        float a = 0.f, b = 0.f;
#pragma unroll 4
        for (int bb = 0; bb < PBR; ++bb) {
            a += red[bb * 512 + c];
            b += red[bb * 512 + HID + c];
        }
        ss[c] = a; sq[c] = b;
    }
    __syncthreads();
    float acc = 0.f;
    for (int k = 0; k < HID; ++k) {
        float m = ss[k] * invcnt;
        float var = sq[k] * invcnt - m * m;
        float A = gamma[k] * rsqrtf(var + BN_EPS);
        float B = beta[k] - m * A;
        float w = W[k * HID + c];
        float wf = A * w;
        u16 hi = f2bf(wf);
        WhiT[c * HID + k] = hi;
        WloT[c * HID + k] = f2bf(wf - bf2f(hi));
        acc = fmaf(B, w, acc);
    }
    rv[c] = acc;
}

// ------- layer 1 FUSED: 6-dim raw-space aggregation + tiny GEMM + relu -> bf16 ---
__global__ __launch_bounds__(256) void k_l1fused(
    const float* __restrict__ pos, const float* __restrict__ nrm,
    const int* __restrict__ ptr, const int* __restrict__ esrc,
    const float* __restrict__ dinv, const float* __restrict__ Wf,
    const float* __restrict__ rvB, const float* __restrict__ b1,
    u16* __restrict__ out) {
    const int wv = threadIdx.x >> 6;
    const int ln = threadIdx.x & 63;
    // hoist per-thread weights for channels c = ln*4+j
    float w[6][4], rv4[4], bb4[4];
#pragma unroll
    for (int k = 0; k < 6; ++k) {
        float4 t = *reinterpret_cast<const float4*>(&Wf[k * HID + ln * 4]);
        w[k][0] = t.x; w[k][1] = t.y; w[k][2] = t.z; w[k][3] = t.w;
    }
    {
        float4 t = *reinterpret_cast<const float4*>(&rvB[ln * 4]);
        rv4[0] = t.x; rv4[1] = t.y; rv4[2] = t.z; rv4[3] = t.w;
        float4 u = *reinterpret_cast<const float4*>(&b1[ln * 4]);
        bb4[0] = u.x; bb4[1] = u.y; bb4[2] = u.z; bb4[3] = u.w;
    }
    for (int n = blockIdx.x * 4 + wv; n < N_NODES; n += gridDim.x * 4) {
        const float dn = dinv[n];
        float z0 = 0, z1 = 0, z2 = 0, z3 = 0, z4 = 0, z5 = 0, t = 0;
        const int s_ = ptr[n], e_ = ptr[n + 1];
        for (int e = s_ + ln; e < e_; e += 64) {
            int src = esrc[e];
            float we = dn * dinv[src];
            z0 = fmaf(we, pos[src * 3 + 0], z0);
            z1 = fmaf(we, pos[src * 3 + 1], z1);
            z2 = fmaf(we, pos[src * 3 + 2], z2);
            z3 = fmaf(we, nrm[src * 3 + 0], z3);
            z4 = fmaf(we, nrm[src * 3 + 1], z4);
            z5 = fmaf(we, nrm[src * 3 + 2], z5);
            t += we;
        }
        if (ln == 0) {   // self loop
            float sl = dn * dn;
            z0 = fmaf(sl, pos[n * 3 + 0], z0);
            z1 = fmaf(sl, pos[n * 3 + 1], z1);
            z2 = fmaf(sl, pos[n * 3 + 2], z2);
            z3 = fmaf(sl, nrm[n * 3 + 0], z3);
            z4 = fmaf(sl, nrm[n * 3 + 1], z4);
            z5 = fmaf(sl, nrm[n * 3 + 2], z5);
            t += sl;
        }
#pragma unroll
        for (int o = 1; o < 64; o <<= 1) {
            z0 += __shfl_xor(z0, o); z1 += __shfl_xor(z1, o); z2 += __shfl_xor(z2, o);
            z3 += __shfl_xor(z3, o); z4 += __shfl_xor(z4, o); z5 += __shfl_xor(z5, o);
            t  += __shfl_xor(t, o);
        }
        ushort4 o4;
        float oj;
        oj = fmaf(t, rv4[0], bb4[0]);
        oj = fmaf(z0, w[0][0], oj); oj = fmaf(z1, w[1][0], oj); oj = fmaf(z2, w[2][0], oj);
        oj = fmaf(z3, w[3][0], oj); oj = fmaf(z4, w[4][0], oj); oj = fmaf(z5, w[5][0], oj);
        o4.x = f2bf(fmaxf(oj, 0.f));
        oj = fmaf(t, rv4[1], bb4[1]);
        oj = fmaf(z0, w[0][1], oj); oj = fmaf(z1, w[1][1], oj); oj = fmaf(z2, w[2][1], oj);
        oj = fmaf(z3, w[3][1], oj); oj = fmaf(z4, w[4][1], oj); oj = fmaf(z5, w[5][1], oj);
        o4.y = f2bf(fmaxf(oj, 0.f));
        oj = fmaf(t, rv4[2], bb4[2]);
        oj = fmaf(z0, w[0][2], oj); oj = fmaf(z1, w[1][2], oj); oj = fmaf(z2, w[2][2], oj);
        oj = fmaf(z3, w[3][2], oj); oj = fmaf(z4, w[4][2], oj); oj = fmaf(z5, w[5][2], oj);
        o4.z = f2bf(fmaxf(oj, 0.f));
        oj = fmaf(t, rv4[3], bb4[3]);
        oj = fmaf(z0, w[0][3], oj); oj = fmaf(z1, w[1][3], oj); oj = fmaf(z2, w[2][3], oj);
        oj = fmaf(z3, w[3][3], oj); oj = fmaf(z4, w[4][3], oj); oj = fmaf(z5, w[5][3], oj);
        o4.w = f2bf(fmaxf(oj, 0.f));
        *reinterpret_cast<ushort4*>(&out[(size_t)n * HID + ln * 4]) = o4;
    }
}

// ------ MFMA GEMM, LDS-staged A tile (padded rows, 2-way-free bank spread) ------
__global__ __launch_bounds__(256) void k_gemm_lds(
    const u16* __restrict__ X, const u16* __restrict__ WhiT,
    const u16* __restrict__ WloT, const float* __restrict__ rv,
    u16* __restrict__ out) {
    __shared__ u16 As[64 * LDSROW];
    const int tid = threadIdx.x;
    const int wv = tid >> 6;
    const int ln = tid & 63;
    const int row0 = blockIdx.x * 64;
    const int lr = ln & 15;
    const int lk = (ln >> 4) * 8;
    const int wcol0 = wv * 64;

    // stage A: 64 rows x 256 ch bf16; coalesced global, padded LDS rows
#pragma unroll
    for (int i = 0; i < 8; ++i) {
        int chunk = i * 256 + tid;        // 0..2047
        int r = chunk >> 5;               // 0..63
        int kc = chunk & 31;              // 16B chunk within row
        bf16x8 v = *reinterpret_cast<const bf16x8*>(&X[(size_t)(row0 + r) * HID + kc * 8]);
        *reinterpret_cast<bf16x8*>(&As[r * LDSROW + kc * 8]) = v;
    }
    __syncthreads();

    f32x4 acc[4][4] = {};
    for (int kk = 0; kk < HID; kk += 32) {
        bf16x8 a[4], bh[4], bl[4];
#pragma unroll
        for (int i = 0; i < 4; ++i)
            a[i] = *reinterpret_cast<const bf16x8*>(&As[(i * 16 + lr) * LDSROW + kk + lk]);
#pragma unroll
        for (int c = 0; c < 4; ++c) {
            int col = wcol0 + c * 16 + lr;
            bh[c] = *reinterpret_cast<const bf16x8*>(&WhiT[(size_t)col * HID + kk + lk]);
            bl[c] = *reinterpret_cast<const bf16x8*>(&WloT[(size_t)col * HID + kk + lk]);
        }
#pragma unroll
        for (int i = 0; i < 4; ++i)
#pragma unroll
            for (int c = 0; c < 4; ++c) {
                acc[i][c] = __builtin_amdgcn_mfma_f32_16x16x32_bf16(a[i], bh[c], acc[i][c], 0, 0, 0);
                acc[i][c] = __builtin_amdgcn_mfma_f32_16x16x32_bf16(a[i], bl[c], acc[i][c], 0, 0, 0);
            }
    }
    const int crow = (ln >> 4) * 4;
#pragma unroll
    for (int c = 0; c < 4; ++c) {
        int col = wcol0 + c * 16 + lr;
        float rvc = rv[col];
#pragma unroll
        for (int i = 0; i < 4; ++i) {
#pragma unroll
            for (int rg = 0; rg < 4; ++rg) {
                int r = row0 + i * 16 + crow + rg;
                out[(size_t)r * HID + col] = f2bf(acc[i][c][rg] + rvc);
            }
        }
    }
}

// -------- aggregation: y = relu(S.xw + bias); 64-edge index prefetch + MLP-8 ----
__global__ __launch_bounds__(256) void k_agg(
    const u16* __restrict__ xw, const int* __restrict__ ptr,
    const int* __restrict__ esrc, const float* __restrict__ dinv,
    const float* __restrict__ bias, u16* __restrict__ y) {
    const int wv = threadIdx.x >> 6;
    const int ln = threadIdx.x & 63;
    const int n = blockIdx.x * 4 + wv;
    const float dn = dinv[n];
    const size_t base = (size_t)n * HID + ln * 4;
    float4 v = ld_bf16x4(&xw[base]);
    const float sl = dn * dn;
    float a0 = v.x * sl, a1 = v.y * sl, a2 = v.z * sl, a3 = v.w * sl;
    const int s = ptr[n], e = ptr[n + 1];
    for (int bs = s; bs < e; bs += 64) {
        const int cnt = (e - bs < 64) ? e - bs : 64;
        int myidx = 0;
        float myw = 0.f;
        if (ln < cnt) {
            myidx = esrc[bs + ln];
            myw = dinv[myidx] * dn;
        }
        int j = 0;
        for (; j + 7 < cnt; j += 8) {
            int   s0 = __shfl(myidx, j),     s1 = __shfl(myidx, j + 1);
            int   s2 = __shfl(myidx, j + 2), s3 = __shfl(myidx, j + 3);
            int   s4 = __shfl(myidx, j + 4), s5 = __shfl(myidx, j + 5);
            int   s6 = __shfl(myidx, j + 6), s7 = __shfl(myidx, j + 7);
            float w0 = __shfl(myw, j),       w1 = __shfl(myw, j + 1);
            float w2 = __shfl(myw, j + 2),   w3 = __shfl(myw, j + 3);
            float w4 = __shfl(myw, j + 4),   w5 = __shfl(myw, j + 5);
            float w6 = __shfl(myw, j + 6),   w7 = __shfl(myw, j + 7);
            float4 u0 = ld_bf16x4(&xw[(size_t)s0 * HID + ln * 4]);
            float4 u1 = ld_bf16x4(&xw[(size_t)s1 * HID + ln * 4]);
            float4 u2 = ld_bf16x4(&xw[(size_t)s2 * HID + ln * 4]);
            float4 u3 = ld_bf16x4(&xw[(size_t)s3 * HID + ln * 4]);
            float4 u4 = ld_bf16x4(&xw[(size_t)s4 * HID + ln * 4]);
            float4 u5 = ld_bf16x4(&xw[(size_t)s5 * HID + ln * 4]);
            float4 u6 = ld_bf16x4(&xw[(size_t)s6 * HID + ln * 4]);
            float4 u7 = ld_bf16x4(&xw[(size_t)s7 * HID + ln * 4]);
            a0 = fmaf(w0, u0.x, a0); a1 = fmaf(w0, u0.y, a1);
            a2 = fmaf(w0, u0.z, a2); a3 = fmaf(w0, u0.w, a3);
            a0 = fmaf(w1, u1.x, a0); a1 = fmaf(w1, u1.y, a1);
            a2 = fmaf(w1, u1.z, a2); a3 = fmaf(w1, u1.w, a3);
            a0 = fmaf(w2, u2.x, a0); a1 = fmaf(w2, u2.y, a1);
            a2 = fmaf(w2, u2.z, a2); a3 = fmaf(w2, u2.w, a3);
            a0 = fmaf(w3, u3.x, a0); a1 = fmaf(w3, u3.y, a1);
            a2 = fmaf(w3, u3.z, a2); a3 = fmaf(w3, u3.w, a3);
            a0 = fmaf(w4, u4.x, a0); a1 = fmaf(w4, u4.y, a1);
            a2 = fmaf(w4, u4.z, a2); a3 = fmaf(w4, u4.w, a3);
            a0 = fmaf(w5, u5.x, a0); a1 = fmaf(w5, u5.y, a1);
            a2 = fmaf(w5, u5.z, a2); a3 = fmaf(w5, u5.w, a3);
            a0 = fmaf(w6, u6.x, a0); a1 = fmaf(w6, u6.y, a1);
            a2 = fmaf(w6, u6.z, a2); a3 = fmaf(w6, u6.w, a3);
            a0 = fmaf(w7, u7.x, a0); a1 = fmaf(w7, u7.y, a1);
            a2 = fmaf(w7, u7.z, a2); a3 = fmaf(w7, u7.w, a3);
        }
        for (; j < cnt; ++j) {
            int   s0 = __shfl(myidx, j);
            float w0 = __shfl(myw, j);
            float4 u0 = ld_bf16x4(&xw[(size_t)s0 * HID + ln * 4]);
            a0 = fmaf(w0, u0.x, a0); a1 = fmaf(w0, u0.y, a1);
            a2 = fmaf(w0, u0.z, a2); a3 = fmaf(w0, u0.w, a3);
        }
    }
    float4 b = *reinterpret_cast<const float4*>(&bias[ln * 4]);
    a0 = fmaxf(a0 + b.x, 0.f);
    a1 = fmaxf(a1 + b.y, 0.f);
    a2 = fmaxf(a2 + b.z, 0.f);
    a3 = fmaxf(a3 + b.w, 0.f);
    ushort4 o;
    o.x = f2bf(a0); o.y = f2bf(a1); o.z = f2bf(a2); o.w = f2bf(a3);
    *reinterpret_cast<ushort4*>(&y[base]) = o;
}

// ------- per-channel stats partials: vectorized (4 row-lanes x 64 ch-quads) ------
__global__ __launch_bounds__(256) void k_stats(const u16* __restrict__ y,
                                               float* __restrict__ part /* PB*512 */) {
    const int t = threadIdx.x;
    const int cl = t & 63;          // channel quad: channels cl*4 .. cl*4+3
    const int rp = t >> 6;          // row parity 0..3
    const int n0 = blockIdx.x * SROWS;
    const int n1 = (n0 + SROWS < N_NODES) ? n0 + SROWS : N_NODES;
    float s0 = 0, s1 = 0, s2 = 0, s3 = 0, q0 = 0, q1 = 0, q2 = 0, q3 = 0;
    for (int n = n0 + rp; n < n1; n += 4) {
        float4 v = ld_bf16x4(&y[(size_t)n * HID + cl * 4]);
        s0 += v.x; q0 = fmaf(v.x, v.x, q0);
        s1 += v.y; q1 = fmaf(v.y, v.y, q1);
        s2 += v.z; q2 = fmaf(v.z, v.z, q2);
        s3 += v.w; q3 = fmaf(v.w, v.w, q3);
    }
    __shared__ float sh[4 * 512];
    float* shr = &sh[rp * 512];
    shr[cl * 4 + 0] = s0; shr[cl * 4 + 1] = s1;
    shr[cl * 4 + 2] = s2; shr[cl * 4 + 3] = s3;
    shr[256 + cl * 4 + 0] = q0; shr[256 + cl * 4 + 1] = q1;
    shr[256 + cl * 4 + 2] = q2; shr[256 + cl * 4 + 3] = q3;
    __syncthreads();
    float a = sh[t] + sh[512 + t] + sh[1024 + t] + sh[1536 + t];
    float b = sh[256 + t] + sh[768 + t] + sh[1280 + t] + sh[1792 + t];
    part[blockIdx.x * 512 + t] = a;
    part[blockIdx.x * 512 + 256 + t] = b;
}

// ---------------- stats + pooled sums fused (batch sorted) ----------------
__global__ __launch_bounds__(256) void k_statspool(const u16* __restrict__ y,
                                                   const int* __restrict__ batch,
                                                   float* __restrict__ part,
                                                   float* __restrict__ ps) {
    const int c = threadIdx.x;
    const int n0 = blockIdx.x * SROWS;
    const int n1 = (n0 + SROWS < N_NODES) ? n0 + SROWS : N_NODES;
    float s = 0.f, q = 0.f;
    if (n0 < N_NODES) {
        int cur = batch[n0];
        float acc = 0.f;
        for (int n = n0; n < n1; ++n) {
            float v = bf2f(y[(size_t)n * HID + c]);
            int g = batch[n];
            if (g != cur) {
                atomicAdd(&ps[cur * HID + c], acc);
                acc = 0.f;
                cur = g;
            }
            s += v;
            q = fmaf(v, v, q);
            acc += v;
        }
        atomicAdd(&ps[cur * HID + c], acc);
    }
    part[blockIdx.x * 512 + c] = s;
    part[blockIdx.x * 512 + HID + c] = q;
}

// ---------------- finalize: BN4 affine on pooled sums (reduces PBR partials) ----
__global__ void k_final(const float* __restrict__ ps, const int* __restrict__ cg,
                        const float* __restrict__ red, const float* __restrict__ gamma,
                        const float* __restrict__ beta, float* __restrict__ out) {
    __shared__ float ss[HID], sq[HID];
    const int c = threadIdx.x;
    {
        float a = 0.f, b = 0.f;
#pragma unroll 4
        for (int bb = 0; bb < PBR; ++bb) {
            a += red[bb * 512 + c];
            b += red[bb * 512 + HID + c];
        }
        ss[c] = a; sq[c] = b;
    }
    __syncthreads();
    const float invn = 1.0f / (float)N_NODES;
    float m = ss[c] * invn;
    float var = sq[c] * invn - m * m;
    float A = gamma[c] * rsqrtf(var + BN_EPS);
    float B = beta[c] - m * A;
    for (int g = 0; g < NG; ++g) {
        float cn = (float)cg[g];
        float val = (A * ps[g * HID + c] + cn * B) / fmaxf(cn, 1.0f);
        out[g * HID + c] = val;
    }
}

extern "C" void kernel_launch(void* const* d_in, const int* in_sizes, int n_in,
                              void* d_out, int out_size, void* d_ws, size_t ws_size,
                              hipStream_t stream) {
    const float* pos   = (const float*)d_in[0];
    const float* nrm   = (const float*)d_in[1];
    const int*   ei    = (const int*)d_in[2];
    const int*   batch = (const int*)d_in[3];
    const float* bn0g  = (const float*)d_in[4];
    const float* bn0b  = (const float*)d_in[5];
    const float* W[4]   = {(const float*)d_in[6],  (const float*)d_in[10], (const float*)d_in[14], (const float*)d_in[18]};
    const float* bb[4]  = {(const float*)d_in[7],  (const float*)d_in[11], (const float*)d_in[15], (const float*)d_in[19]};
    const float* bg[4]  = {(const float*)d_in[8],  (const float*)d_in[12], (const float*)d_in[16], (const float*)d_in[20]};
    const float* bbt[4] = {(const float*)d_in[9],  (const float*)d_in[13], (const float*)d_in[17], (const float*)d_in[21]};

    char* wp = (char*)d_ws;
    auto alloc = [&](size_t bytes) {
        char* p = wp;
        wp += (bytes + 255) & ~(size_t)255;
        return p;
    };
    float* dinv  = (float*)alloc((size_t)N_NODES * 4);
    int*   cnt   = (int*)  alloc((size_t)N_NODES * 4);
    int*   ptr   = (int*)  alloc((size_t)(N_NODES + 1) * 4);
    int*   ptr2  = (int*)  alloc((size_t)N_NODES * 4);
    int*   esrc  = (int*)  alloc((size_t)N_EDGES * 4);
    u16*   bufA  = (u16*)  alloc((size_t)NPAD * HID * 2);
    u16*   bufB  = (u16*)  alloc((size_t)NPAD * HID * 2);
    float* part0 = (float*)alloc((size_t)B0 * 12 * 4);
    float* partL = (float*)alloc((size_t)PB * 512 * 4);
    float* red   = (float*)alloc((size_t)PBR * 512 * 4);
    float* Wf1   = (float*)alloc((size_t)6 * HID * 4);
    u16*   WhiT  = (u16*)  alloc((size_t)HID * HID * 2);
    u16*   WloT  = (u16*)  alloc((size_t)HID * HID * 2);
    float* rv    = (float*)alloc(HID * 4);
    float* psz   = (float*)alloc((size_t)(NG * HID + NG) * 4);
    float* ps    = psz;
    int*   cg    = (int*)(psz + NG * HID);
    (void)ws_size; (void)in_sizes; (void)n_in; (void)out_size;

    const int* rowi = ei;
    const int* coli = ei + N_EDGES;

    hipMemsetAsync(cnt, 0, (size_t)N_NODES * 4, stream);
    hipMemsetAsync(psz, 0, (size_t)(NG * HID + NG) * 4, stream);

    // CSR + norms
    k_count<<<2048, 256, 0, stream>>>(coli, cnt);
    k_scan<<<1, 1024, 0, stream>>>(cnt, ptr, ptr2, dinv);
    for (int p = 0; p < 4; ++p)
        k_fillp<<<1024, 256, 0, stream>>>(rowi, coli, ptr2, esrc, p * FPART);

    // layer 1: fused raw-space aggregation + BN0-folded tiny GEMM
    k_bn0stats<<<B0, 256, 0, stream>>>(pos, nrm, batch, part0, cg);
    k_fold6<<<1, 256, 0, stream>>>(W[0], part0, 1.0f / (float)N_NODES, bn0g, bn0b, Wf1, rv);
    k_l1fused<<<2048, 256, 0, stream>>>(pos, nrm, ptr, esrc, dinv, Wf1, rv, bb[0], bufA);

    // layers 2..4: stats -> reduce -> fold BN_l into W_{l+1} -> MFMA gemm -> aggregate
    for (int l = 0; l < 3; ++l) {
        k_stats<<<PB, 256, 0, stream>>>(bufA, partL);
        k_reduce<<<PBR, 256, 0, stream>>>(partL, red);
        k_fold256<<<1, 256, 0, stream>>>(W[l + 1], red, 1.0f / (float)N_NODES,
                                         bg[l], bbt[l], WhiT, WloT, rv);
        k_gemm_lds<<<NPAD / 64, 256, 0, stream>>>(bufA, WhiT, WloT, rv, bufB);
        k_agg<<<N_NODES / 4, 256, 0, stream>>>(bufB, ptr, esrc, dinv, bb[l + 1], bufA);
    }

    // final: fused stats+pool, then BN4 applied analytically on pooled sums
    k_statspool<<<PB, 256, 0, stream>>>(bufA, batch, partL, ps);
    k_reduce<<<PBR, 256, 0, stream>>>(partL, red);
    k_final<<<1, 256, 0, stream>>>(ps, cg, red, bg[3], bbt[3], (float*)d_out);
}

// Round 13
// 1579.621 us; speedup vs baseline: 2.9043x; 1.0222x over previous
//
#include <hip/hip_runtime.h>
#include <hip/hip_bf16.h>
#include <cstdint>

#define N_NODES 100000
#define NPAD    100032   // padded row count (multiple of 64)
#define N_EDGES 3200000
#define HID 256
#define NG 16
#define BN_EPS 1e-5f
#define B0 120       // bn0stats partial blocks
#define NB 391       // scan blocks (391*256 >= N_NODES)
#define SLABS 128    // stats atomic slabs
#define FPART 25000  // k_fill column-partition width (4 * 25000 = 100000)
#define LDSROW 264   // padded LDS row stride in elements
#define AGB 2048     // k_agg / k_l1fused grid blocks
#define NGRP (N_NODES / 4)   // 25000 node-groups of 4

typedef unsigned short u16;
using bf16x8 = __attribute__((ext_vector_type(8))) short;
using f32x4  = __attribute__((ext_vector_type(4))) float;

__device__ __forceinline__ float bf2f(u16 b) {
    return __uint_as_float(((unsigned)b) << 16);
}
__device__ __forceinline__ u16 f2bf(float f) {
    unsigned u = __float_as_uint(f);
    unsigned r = (u + 0x7FFFu + ((u >> 16) & 1u)) >> 16;
    return (u16)r;
}
__device__ __forceinline__ float4 ld_bf16x4(const u16* p) {
    ushort4 u = *reinterpret_cast<const ushort4*>(p);
    float4 f;
    f.x = bf2f(u.x); f.y = bf2f(u.y); f.z = bf2f(u.z); f.w = bf2f(u.w);
    return f;
}

// ---------------- CSR build ----------------
__global__ void k_count(const int* __restrict__ coli, int* __restrict__ cnt) {
    int i = blockIdx.x * blockDim.x + threadIdx.x;
    int st = gridDim.x * blockDim.x;
    for (; i < N_EDGES; i += st) atomicAdd(&cnt[coli[i]], 1);
}

// ---- parallel 3-pass scan: A) block sums  B) scan sums  C) apply + dinv ----
__global__ __launch_bounds__(256) void k_scanA(const int* __restrict__ cnt,
                                               int* __restrict__ bsum) {
    const int t = threadIdx.x;
    const int i = blockIdx.x * 256 + t;
    int v = (i < N_NODES) ? cnt[i] : 0;
    for (int o = 32; o > 0; o >>= 1) v += __shfl_down(v, o);
    __shared__ int ws[4];
    if ((t & 63) == 0) ws[t >> 6] = v;
    __syncthreads();
    if (t == 0) bsum[blockIdx.x] = ws[0] + ws[1] + ws[2] + ws[3];
}

__global__ __launch_bounds__(512) void k_scanB(const int* __restrict__ bsum,
                                               int* __restrict__ boff,
                                               int* __restrict__ ptrN) {
    const int t = threadIdx.x;          // 512 threads
    const int ln = t & 63, wv = t >> 6; // 8 waves
    int v = (t < NB) ? bsum[t] : 0;
    int sc = v;
    for (int o = 1; o < 64; o <<= 1) { int u = __shfl_up(sc, o); if (ln >= o) sc += u; }
    __shared__ int ws[8], wx[9];
    if (ln == 63) ws[wv] = sc;
    __syncthreads();
    if (t == 0) { int a = 0; for (int k = 0; k < 8; ++k) { wx[k] = a; a += ws[k]; } wx[8] = a; }
    __syncthreads();
    int excl = wx[wv] + sc - v;
    if (t < NB) boff[t] = excl;
    if (t == 0) ptrN[0] = wx[8];
}

__global__ __launch_bounds__(256) void k_scanC(const int* __restrict__ cnt,
                                               const int* __restrict__ boff,
                                               int* __restrict__ ptr,
                                               int* __restrict__ ptr2,
                                               float* __restrict__ dinv) {
    const int t = threadIdx.x;
    const int i = blockIdx.x * 256 + t;
    const int ln = t & 63, wv = t >> 6;
    int v = (i < N_NODES) ? cnt[i] : 0;
    if (i < N_NODES) dinv[i] = rsqrtf((float)v + 1.0f);
    int sc = v;
    for (int o = 1; o < 64; o <<= 1) { int u = __shfl_up(sc, o); if (ln >= o) sc += u; }
    __shared__ int ws[4], wx[4];
    if (ln == 63) ws[wv] = sc;
    __syncthreads();
    if (t == 0) { int a = 0; for (int k = 0; k < 4; ++k) { wx[k] = a; a += ws[k]; } }
    __syncthreads();
    int excl = boff[blockIdx.x] + wx[wv] + sc - v;
    if (i < N_NODES) { ptr[i] = excl; ptr2[i] = excl; }
}

// partitioned fill: this pass only handles cols in [lo, lo+FPART).
__global__ void k_fillp(const int* __restrict__ rowi, const int* __restrict__ coli,
                        int* __restrict__ ptr2, int* __restrict__ esrc, int lo) {
    int i = blockIdx.x * blockDim.x + threadIdx.x;
    int st = gridDim.x * blockDim.x;
    const int hi = lo + FPART;
    for (; i < N_EDGES; i += st) {
        int c = coli[i];
        if (c >= lo && c < hi) {
            int r = rowi[i];
            int p = atomicAdd(&ptr2[c], 1);
            esrc[p] = r;
        }
    }
}

// ---------------- BN0 stats + batch histogram fused ----------------
__global__ __launch_bounds__(256) void k_bn0stats(const float* __restrict__ pos,
                                                  const float* __restrict__ nrm,
                                                  const int* __restrict__ batch,
                                                  float* __restrict__ part /* B0*12 */,
                                                  int* __restrict__ cg) {
    __shared__ int h[NG];
    if (threadIdx.x < NG) h[threadIdx.x] = 0;
    __syncthreads();
    float s[6] = {0, 0, 0, 0, 0, 0}, q[6] = {0, 0, 0, 0, 0, 0};
    int i = blockIdx.x * blockDim.x + threadIdx.x;
    int stp = gridDim.x * blockDim.x;
    for (; i < N_NODES; i += stp) {
        float v;
        v = pos[i * 3 + 0]; s[0] += v; q[0] += v * v;
        v = pos[i * 3 + 1]; s[1] += v; q[1] += v * v;
        v = pos[i * 3 + 2]; s[2] += v; q[2] += v * v;
        v = nrm[i * 3 + 0]; s[3] += v; q[3] += v * v;
        v = nrm[i * 3 + 1]; s[4] += v; q[4] += v * v;
        v = nrm[i * 3 + 2]; s[5] += v; q[5] += v * v;
        atomicAdd(&h[batch[i]], 1);
    }
#pragma unroll
    for (int k = 0; k < 6; ++k) {
        for (int o = 32; o > 0; o >>= 1) { s[k] += __shfl_down(s[k], o); q[k] += __shfl_down(q[k], o); }
    }
    __shared__ float ls[4][12];
    const int wv = threadIdx.x >> 6;
    const int ln = threadIdx.x & 63;
    if (ln == 0) {
#pragma unroll
        for (int k = 0; k < 6; ++k) { ls[wv][k] = s[k]; ls[wv][6 + k] = q[k]; }
    }
    __syncthreads();
    if (threadIdx.x < 12)
        part[blockIdx.x * 12 + threadIdx.x] =
            ls[0][threadIdx.x] + ls[1][threadIdx.x] + ls[2][threadIdx.x] + ls[3][threadIdx.x];
    if (threadIdx.x < NG) {
        int v = h[threadIdx.x];
        if (v) atomicAdd(&cg[threadIdx.x], v);
    }
}

// ---------------- fold BN0 into W1 (K=6): Wf=A*W, rvB = B^T W ----------------
__global__ void k_fold6(const float* __restrict__ W,
                        const float* __restrict__ part, float invcnt,
                        const float* __restrict__ gamma, const float* __restrict__ beta,
                        float* __restrict__ Wf, float* __restrict__ rvB) {
    __shared__ float st[12];
    int c = threadIdx.x;
    if (c < 12) {
        float a = 0.f;
        for (int b = 0; b < B0; ++b) a += part[b * 12 + c];
        st[c] = a;
    }
    __syncthreads();
    float acc = 0.f;
    for (int k = 0; k < 6; ++k) {
        float m = st[k] * invcnt;
        float var = st[6 + k] * invcnt - m * m;
        float A = gamma[k] * rsqrtf(var + BN_EPS);
        float B = beta[k] - m * A;
        float w = W[k * HID + c];
        Wf[k * HID + c] = A * w;
        acc = fmaf(B, w, acc);
    }
    rvB[c] = acc;
}

// -------- fold for K=256: reduces SLABS atomic-slab partials in preamble --------
__global__ void k_fold256(const float* __restrict__ W,
                          const float* __restrict__ partL /* SLABS*512 */, float invcnt,
                          const float* __restrict__ gamma, const float* __restrict__ beta,
                          u16* __restrict__ WhiT, u16* __restrict__ WloT,
                          float* __restrict__ rv) {
    __shared__ float ss[HID], sq[HID];
    int c = threadIdx.x;
    {
        float a = 0.f, b = 0.f;
#pragma unroll 4
        for (int bb = 0; bb < SLABS; ++bb) {
            a += partL[bb * 512 + c];
            b += partL[bb * 512 + HID + c];
        }
        ss[c] = a; sq[c] = b;
    }
    __syncthreads();
    float acc = 0.f;
    for (int k = 0; k < HID; ++k) {
        float m = ss[k] * invcnt;
        float var = sq[k] * invcnt - m * m;
        float A = gamma[k] * rsqrtf(var + BN_EPS);
        float B = beta[k] - m * A;
        float w = W[k * HID + c];
        float wf = A * w;
        u16 hi = f2bf(wf);
        WhiT[c * HID + k] = hi;
        WloT[c * HID + k] = f2bf(wf - bf2f(hi));
        acc = fmaf(B, w, acc);
    }
    rv[c] = acc;
}

// ------- layer 1 FUSED: 6-dim aggregation + tiny GEMM + relu + stats -> bf16 ----
__global__ __launch_bounds__(256) void k_l1fused(
    const float* __restrict__ pos, const float* __restrict__ nrm,
    const int* __restrict__ ptr, const int* __restrict__ esrc,
    const float* __restrict__ dinv, const float* __restrict__ Wf,
    const float* __restrict__ rvB, const float* __restrict__ b1,
    u16* __restrict__ out, float* __restrict__ partL) {
    const int wv = threadIdx.x >> 6;
    const int ln = threadIdx.x & 63;
    float w[6][4], rv4[4], bb4[4];
#pragma unroll
    for (int k = 0; k < 6; ++k) {
        float4 t = *reinterpret_cast<const float4*>(&Wf[k * HID + ln * 4]);
        w[k][0] = t.x; w[k][1] = t.y; w[k][2] = t.z; w[k][3] = t.w;
    }
    {
        float4 t = *reinterpret_cast<const float4*>(&rvB[ln * 4]);
        rv4[0] = t.x; rv4[1] = t.y; rv4[2] = t.z; rv4[3] = t.w;
        float4 u = *reinterpret_cast<const float4*>(&b1[ln * 4]);
        bb4[0] = u.x; bb4[1] = u.y; bb4[2] = u.z; bb4[3] = u.w;
    }
    float ssr[4] = {0, 0, 0, 0}, qqr[4] = {0, 0, 0, 0};
    for (int n = blockIdx.x * 4 + wv; n < N_NODES; n += AGB * 4) {
        const float dn = dinv[n];
        float z0 = 0, z1 = 0, z2 = 0, z3 = 0, z4 = 0, z5 = 0, t = 0;
        const int s_ = ptr[n], e_ = ptr[n + 1];
        for (int e = s_ + ln; e < e_; e += 64) {
            int src = esrc[e];
            float we = dn * dinv[src];
            z0 = fmaf(we, pos[src * 3 + 0], z0);
            z1 = fmaf(we, pos[src * 3 + 1], z1);
            z2 = fmaf(we, pos[src * 3 + 2], z2);
            z3 = fmaf(we, nrm[src * 3 + 0], z3);
            z4 = fmaf(we, nrm[src * 3 + 1], z4);
            z5 = fmaf(we, nrm[src * 3 + 2], z5);
            t += we;
        }
        if (ln == 0) {   // self loop
            float sl = dn * dn;
            z0 = fmaf(sl, pos[n * 3 + 0], z0);
            z1 = fmaf(sl, pos[n * 3 + 1], z1);
            z2 = fmaf(sl, pos[n * 3 + 2], z2);
            z3 = fmaf(sl, nrm[n * 3 + 0], z3);
            z4 = fmaf(sl, nrm[n * 3 + 1], z4);
            z5 = fmaf(sl, nrm[n * 3 + 2], z5);
            t += sl;
        }
#pragma unroll
        for (int o = 1; o < 64; o <<= 1) {
            z0 += __shfl_xor(z0, o); z1 += __shfl_xor(z1, o); z2 += __shfl_xor(z2, o);
            z3 += __shfl_xor(z3, o); z4 += __shfl_xor(z4, o); z5 += __shfl_xor(z5, o);
            t  += __shfl_xor(t, o);
        }
        ushort4 o4;
#pragma unroll
        for (int j = 0; j < 4; ++j) {
            float oj = fmaf(t, rv4[j], bb4[j]);
            oj = fmaf(z0, w[0][j], oj); oj = fmaf(z1, w[1][j], oj); oj = fmaf(z2, w[2][j], oj);
            oj = fmaf(z3, w[3][j], oj); oj = fmaf(z4, w[4][j], oj); oj = fmaf(z5, w[5][j], oj);
            oj = fmaxf(oj, 0.f);
            ssr[j] += oj; qqr[j] = fmaf(oj, oj, qqr[j]);
            ((u16*)&o4)[j] = f2bf(oj);
        }
        *reinterpret_cast<ushort4*>(&out[(size_t)n * HID + ln * 4]) = o4;
    }
    // block stats reduce -> atomics into slab
    __shared__ float sh[4 * 512];
    float* shw = &sh[wv * 512];
#pragma unroll
    for (int j = 0; j < 4; ++j) { shw[ln * 4 + j] = ssr[j]; shw[256 + ln * 4 + j] = qqr[j]; }
    __syncthreads();
    const int t = threadIdx.x;
    float S = sh[t] + sh[512 + t] + sh[1024 + t] + sh[1536 + t];
    float Q = sh[256 + t] + sh[768 + t] + sh[1280 + t] + sh[1792 + t];
    float* slab = &partL[(size_t)(blockIdx.x & (SLABS - 1)) * 512];
    atomicAdd(&slab[t], S);
    atomicAdd(&slab[256 + t], Q);
}

// ------ MFMA GEMM, LDS-staged A tile (padded rows, 2-way-free bank spread) ------
__global__ __launch_bounds__(256) void k_gemm_lds(
    const u16* __restrict__ X, const u16* __restrict__ WhiT,
    const u16* __restrict__ WloT, const float* __restrict__ rv,
    u16* __restrict__ out) {
    __shared__ u16 As[64 * LDSROW];
    const int tid = threadIdx.x;
    const int wv = tid >> 6;
    const int ln = tid & 63;
    const int row0 = blockIdx.x * 64;
    const int lr = ln & 15;
    const int lk = (ln >> 4) * 8;
    const int wcol0 = wv * 64;

#pragma unroll
    for (int i = 0; i < 8; ++i) {
        int chunk = i * 256 + tid;
        int r = chunk >> 5;
        int kc = chunk & 31;
        bf16x8 v = *reinterpret_cast<const bf16x8*>(&X[(size_t)(row0 + r) * HID + kc * 8]);
        *reinterpret_cast<bf16x8*>(&As[r * LDSROW + kc * 8]) = v;
    }
    __syncthreads();

    f32x4 acc[4][4] = {};
    for (int kk = 0; kk < HID; kk += 32) {
        bf16x8 a[4], bh[4], bl[4];
#pragma unroll
        for (int i = 0; i < 4; ++i)
            a[i] = *reinterpret_cast<const bf16x8*>(&As[(i * 16 + lr) * LDSROW + kk + lk]);
#pragma unroll
        for (int c = 0; c < 4; ++c) {
            int col = wcol0 + c * 16 + lr;
            bh[c] = *reinterpret_cast<const bf16x8*>(&WhiT[(size_t)col * HID + kk + lk]);
            bl[c] = *reinterpret_cast<const bf16x8*>(&WloT[(size_t)col * HID + kk + lk]);
        }
#pragma unroll
        for (int i = 0; i < 4; ++i)
#pragma unroll
            for (int c = 0; c < 4; ++c) {
                acc[i][c] = __builtin_amdgcn_mfma_f32_16x16x32_bf16(a[i], bh[c], acc[i][c], 0, 0, 0);
                acc[i][c] = __builtin_amdgcn_mfma_f32_16x16x32_bf16(a[i], bl[c], acc[i][c], 0, 0, 0);
            }
    }
    const int crow = (ln >> 4) * 4;
#pragma unroll
    for (int c = 0; c < 4; ++c) {
        int col = wcol0 + c * 16 + lr;
        float rvc = rv[col];
#pragma unroll
        for (int i = 0; i < 4; ++i) {
#pragma unroll
            for (int rg = 0; rg < 4; ++rg) {
                int r = row0 + i * 16 + crow + rg;
                out[(size_t)r * HID + col] = f2bf(acc[i][c][rg] + rvc);
            }
        }
    }
}

// ---- aggregation: y = relu(S.xw + bias) + fused stats; grid-stride AGB blocks ----
__global__ __launch_bounds__(256) void k_agg(
    const u16* __restrict__ xw, const int* __restrict__ ptr,
    const int* __restrict__ esrc, const float* __restrict__ dinv,
    const float* __restrict__ bias, u16* __restrict__ y,
    float* __restrict__ partL) {
    const int wv = threadIdx.x >> 6;
    const int ln = threadIdx.x & 63;
    float4 b = *reinterpret_cast<const float4*>(&bias[ln * 4]);
    float ssr[4] = {0, 0, 0, 0}, qqr[4] = {0, 0, 0, 0};
    for (int g = blockIdx.x; g < NGRP; g += AGB) {
        const int n = g * 4 + wv;
        const float dn = dinv[n];
        const size_t base = (size_t)n * HID + ln * 4;
        float4 v = ld_bf16x4(&xw[base]);
        const float sl = dn * dn;
        float a0 = v.x * sl, a1 = v.y * sl, a2 = v.z * sl, a3 = v.w * sl;
        const int s = ptr[n], e = ptr[n + 1];
        for (int bs = s; bs < e; bs += 64) {
            const int cnt = (e - bs < 64) ? e - bs : 64;
            int myidx = 0;
            float myw = 0.f;
            if (ln < cnt) {
                myidx = esrc[bs + ln];
                myw = dinv[myidx] * dn;
            }
            int j = 0;
            for (; j + 3 < cnt; j += 4) {
                int   s0 = __shfl(myidx, j),     s1 = __shfl(myidx, j + 1);
                int   s2 = __shfl(myidx, j + 2), s3 = __shfl(myidx, j + 3);
                float w0 = __shfl(myw, j),       w1 = __shfl(myw, j + 1);
                float w2 = __shfl(myw, j + 2),   w3 = __shfl(myw, j + 3);
                float4 u0 = ld_bf16x4(&xw[(size_t)s0 * HID + ln * 4]);
                float4 u1 = ld_bf16x4(&xw[(size_t)s1 * HID + ln * 4]);
                float4 u2 = ld_bf16x4(&xw[(size_t)s2 * HID + ln * 4]);
                float4 u3 = ld_bf16x4(&xw[(size_t)s3 * HID + ln * 4]);
                a0 = fmaf(w0, u0.x, a0); a1 = fmaf(w0, u0.y, a1);
                a2 = fmaf(w0, u0.z, a2); a3 = fmaf(w0, u0.w, a3);
                a0 = fmaf(w1, u1.x, a0); a1 = fmaf(w1, u1.y, a1);
                a2 = fmaf(w1, u1.z, a2); a3 = fmaf(w1, u1.w, a3);
                a0 = fmaf(w2, u2.x, a0); a1 = fmaf(w2, u2.y, a1);
                a2 = fmaf(w2, u2.z, a2); a3 = fmaf(w2, u2.w, a3);
                a0 = fmaf(w3, u3.x, a0); a1 = fmaf(w3, u3.y, a1);
                a2 = fmaf(w3, u3.z, a2); a3 = fmaf(w3, u3.w, a3);
            }
            for (; j < cnt; ++j) {
                int   s0 = __shfl(myidx, j);
                float w0 = __shfl(myw, j);
                float4 u0 = ld_bf16x4(&xw[(size_t)s0 * HID + ln * 4]);
                a0 = fmaf(w0, u0.x, a0); a1 = fmaf(w0, u0.y, a1);
                a2 = fmaf(w0, u0.z, a2); a3 = fmaf(w0, u0.w, a3);
            }
        }
        a0 = fmaxf(a0 + b.x, 0.f);
        a1 = fmaxf(a1 + b.y, 0.f);
        a2 = fmaxf(a2 + b.z, 0.f);
        a3 = fmaxf(a3 + b.w, 0.f);
        ssr[0] += a0; qqr[0] = fmaf(a0, a0, qqr[0]);
        ssr[1] += a1; qqr[1] = fmaf(a1, a1, qqr[1]);
        ssr[2] += a2; qqr[2] = fmaf(a2, a2, qqr[2]);
        ssr[3] += a3; qqr[3] = fmaf(a3, a3, qqr[3]);
        ushort4 o;
        o.x = f2bf(a0); o.y = f2bf(a1); o.z = f2bf(a2); o.w = f2bf(a3);
        *reinterpret_cast<ushort4*>(&y[base]) = o;
    }
    __shared__ float sh[4 * 512];
    float* shw = &sh[wv * 512];
#pragma unroll
    for (int j = 0; j < 4; ++j) { shw[ln * 4 + j] = ssr[j]; shw[256 + ln * 4 + j] = qqr[j]; }
    __syncthreads();
    const int t = threadIdx.x;
    float S = sh[t] + sh[512 + t] + sh[1024 + t] + sh[1536 + t];
    float Q = sh[256 + t] + sh[768 + t] + sh[1280 + t] + sh[1792 + t];
    float* slab = &partL[(size_t)(blockIdx.x & (SLABS - 1)) * 512];
    atomicAdd(&slab[t], S);
    atomicAdd(&slab[256 + t], Q);
}

// ---------------- pooled sums by graph (batch sorted), pool-only ----------------
__global__ __launch_bounds__(256) void k_pool(const u16* __restrict__ y,
                                              const int* __restrict__ batch,
                                              float* __restrict__ ps) {
    const int c = threadIdx.x;
    const int n0 = blockIdx.x * 98;
    if (n0 >= N_NODES) return;
    const int n1 = (n0 + 98 < N_NODES) ? n0 + 98 : N_NODES;
    int cur = batch[n0];
    float acc = 0.f;
    for (int n = n0; n < n1; ++n) {
        float v = bf2f(y[(size_t)n * HID + c]);
        int g = batch[n];
        if (g != cur) {
            atomicAdd(&ps[cur * HID + c], acc);
            acc = 0.f;
            cur = g;
        }
        acc += v;
    }
    atomicAdd(&ps[cur * HID + c], acc);
}

// ---------------- finalize: BN4 affine on pooled sums (reads slabs) ----------------
__global__ void k_final(const float* __restrict__ ps, const int* __restrict__ cg,
                        const float* __restrict__ partL, const float* __restrict__ gamma,
                        const float* __restrict__ beta, float* __restrict__ out) {
    __shared__ float ss[HID], sq[HID];
    const int c = threadIdx.x;
    {
        float a = 0.f, b = 0.f;
#pragma unroll 4
        for (int bb = 0; bb < SLABS; ++bb) {
            a += partL[bb * 512 + c];
            b += partL[bb * 512 + HID + c];
        }
        ss[c] = a; sq[c] = b;
    }
    __syncthreads();
    const float invn = 1.0f / (float)N_NODES;
    float m = ss[c] * invn;
    float var = sq[c] * invn - m * m;
    float A = gamma[c] * rsqrtf(var + BN_EPS);
    float B = beta[c] - m * A;
    for (int g = 0; g < NG; ++g) {
        float cn = (float)cg[g];
        float val = (A * ps[g * HID + c] + cn * B) / fmaxf(cn, 1.0f);
        out[g * HID + c] = val;
    }
}

extern "C" void kernel_launch(void* const* d_in, const int* in_sizes, int n_in,
                              void* d_out, int out_size, void* d_ws, size_t ws_size,
                              hipStream_t stream) {
    const float* pos   = (const float*)d_in[0];
    const float* nrm   = (const float*)d_in[1];
    const int*   ei    = (const int*)d_in[2];
    const int*   batch = (const int*)d_in[3];
    const float* bn0g  = (const float*)d_in[4];
    const float* bn0b  = (const float*)d_in[5];
    const float* W[4]   = {(const float*)d_in[6],  (const float*)d_in[10], (const float*)d_in[14], (const float*)d_in[18]};
    const float* bb[4]  = {(const float*)d_in[7],  (const float*)d_in[11], (const float*)d_in[15], (const float*)d_in[19]};
    const float* bg[4]  = {(const float*)d_in[8],  (const float*)d_in[12], (const float*)d_in[16], (const float*)d_in[20]};
    const float* bbt[4] = {(const float*)d_in[9],  (const float*)d_in[13], (const float*)d_in[17], (const float*)d_in[21]};

    char* wp = (char*)d_ws;
    auto alloc = [&](size_t bytes) {
        char* p = wp;
        wp += (bytes + 255) & ~(size_t)255;
        return p;
    };
    float* dinv  = (float*)alloc((size_t)N_NODES * 4);
    int*   cnt   = (int*)  alloc((size_t)N_NODES * 4);
    int*   ptr   = (int*)  alloc((size_t)(N_NODES + 1) * 4);
    int*   ptr2  = (int*)  alloc((size_t)N_NODES * 4);
    int*   esrc  = (int*)  alloc((size_t)N_EDGES * 4);
    int*   bsum  = (int*)  alloc((size_t)NB * 4);
    int*   boff  = (int*)  alloc((size_t)NB * 4);
    u16*   bufA  = (u16*)  alloc((size_t)NPAD * HID * 2);
    u16*   bufB  = (u16*)  alloc((size_t)NPAD * HID * 2);
    float* part0 = (float*)alloc((size_t)B0 * 12 * 4);
    float* partL = (float*)alloc((size_t)SLABS * 512 * 4);
    float* Wf1   = (float*)alloc((size_t)6 * HID * 4);
    u16*   WhiT  = (u16*)  alloc((size_t)HID * HID * 2);
    u16*   WloT  = (u16*)  alloc((size_t)HID * HID * 2);
    float* rv    = (float*)alloc(HID * 4);
    float* psz   = (float*)alloc((size_t)(NG * HID + NG) * 4);
    float* ps    = psz;
    int*   cg    = (int*)(psz + NG * HID);
    (void)ws_size; (void)in_sizes; (void)n_in; (void)out_size;

    const int* rowi = ei;
    const int* coli = ei + N_EDGES;

    hipMemsetAsync(cnt, 0, (size_t)N_NODES * 4, stream);
    hipMemsetAsync(psz, 0, (size_t)(NG * HID + NG) * 4, stream);
    hipMemsetAsync(partL, 0, (size_t)SLABS * 512 * 4, stream);

    // CSR + norms (parallel 3-pass scan)
    k_count<<<2048, 256, 0, stream>>>(coli, cnt);
    k_scanA<<<NB, 256, 0, stream>>>(cnt, bsum);
    k_scanB<<<1, 512, 0, stream>>>(bsum, boff, &ptr[N_NODES]);
    k_scanC<<<NB, 256, 0, stream>>>(cnt, boff, ptr, ptr2, dinv);
    for (int p = 0; p < 4; ++p)
        k_fillp<<<1024, 256, 0, stream>>>(rowi, coli, ptr2, esrc, p * FPART);

    // layer 1: fused raw-space aggregation + BN0-folded tiny GEMM + stats
    k_bn0stats<<<B0, 256, 0, stream>>>(pos, nrm, batch, part0, cg);
    k_fold6<<<1, 256, 0, stream>>>(W[0], part0, 1.0f / (float)N_NODES, bn0g, bn0b, Wf1, rv);
    k_l1fused<<<AGB, 256, 0, stream>>>(pos, nrm, ptr, esrc, dinv, Wf1, rv, bb[0], bufA, partL);

    // layers 2..4: fold BN_l into W_{l+1} -> MFMA gemm -> aggregate(+stats)
    for (int l = 0; l < 3; ++l) {
        k_fold256<<<1, 256, 0, stream>>>(W[l + 1], partL, 1.0f / (float)N_NODES,
                                         bg[l], bbt[l], WhiT, WloT, rv);
        hipMemsetAsync(partL, 0, (size_t)SLABS * 512 * 4, stream);
        k_gemm_lds<<<NPAD / 64, 256, 0, stream>>>(bufA, WhiT, WloT, rv, bufB);
        k_agg<<<AGB, 256, 0, stream>>>(bufB, ptr, esrc, dinv, bb[l + 1], bufA, partL);
    }

    // final: pool, then BN4 applied analytically on pooled sums
    k_pool<<<(N_NODES + 97) / 98, 256, 0, stream>>>(bufA, batch, ps);
    k_final<<<1, 256, 0, stream>>>(ps, cg, partL, bg[3], bbt[3], (float*)d_out);
}